// Round 13
// baseline (593.524 us; speedup 1.0000x reference)
//
#include <hip/hip_runtime.h>
#include <hip/hip_bf16.h>

// ---------------------------------------------------------------------------
// RevGAT forward on MI355X.
// R2-R4: BN widened, k_agg single-pass, big fusion (706us).
// R5/R6/R10: col-split replication / no-LDS / 4-wave REGRESSED.
// R7-R9: LDS 8-wave col-split, swapped MFMA, el/er aug cols (581us).
// R11/R12: BM=32 queue, bf16 h + coalesced flush (559us). Write-path theory
//     falsified as limiter (WRITE halved, dur flat). GEMM stuck 60-77us.
// R13: BN partial stats FUSED into k_agg epilogue (deterministic per-block
//     slots, no float atomics) -> k_bn_part x5 deleted; widened k_bn_finP
//     reduces 6250 slots/col (final norm reads 2 producer regions).
//     ftb LDS-staging reverted (R12 added 400K conflicts, no gain).
// ---------------------------------------------------------------------------

#define IN_F   256
#define HIDW   256          // HEADS*HID
#define CLS    40

typedef __attribute__((ext_vector_type(8))) __bf16 bf16x8;
typedef __attribute__((ext_vector_type(4))) float  f32x4;

__device__ inline bf16x8 zb8() {
    bf16x8 v;
#pragma unroll
    for (int i = 0; i < 8; ++i) v[i] = (__bf16)0.f;
    return v;
}
__device__ inline bf16x8 ldb8(const __hip_bfloat16* p) {
    return *reinterpret_cast<const bf16x8*>(p);
}
__device__ inline float bf2f(unsigned short u) {
    union { unsigned int i; float f; } c;
    c.i = ((unsigned int)u) << 16;
    return c.f;
}
__device__ inline unsigned short f2bu(float f) {
    __hip_bfloat16 t = __float2bfloat16(f);
    union { __hip_bfloat16 b; unsigned short u; } c;
    c.b = t;
    return c.u;
}

// ------------------------------ graph prep --------------------------------
__global__ void k_hist(const int* __restrict__ src, const int* __restrict__ dst,
                       int E, int* __restrict__ outdeg, int* __restrict__ indeg) {
    for (int e = blockIdx.x * blockDim.x + threadIdx.x; e < E; e += gridDim.x * blockDim.x) {
        atomicAdd(&outdeg[src[e]], 1);
        atomicAdd(&indeg[dst[e]], 1);
    }
}

__global__ void k_scan1(const int* __restrict__ cnt, int N, int* __restrict__ rp1,
                        int* __restrict__ bsum) {
    __shared__ int sm[256];
    int i = blockIdx.x * 256 + threadIdx.x;
    int v = (i < N) ? cnt[i] : 0;
    sm[threadIdx.x] = v;
    __syncthreads();
    for (int off = 1; off < 256; off <<= 1) {
        int t = (threadIdx.x >= off) ? sm[threadIdx.x - off] : 0;
        __syncthreads();
        sm[threadIdx.x] += t;
        __syncthreads();
    }
    if (i < N) rp1[i] = sm[threadIdx.x];                  // inclusive within block
    if (threadIdx.x == 255) bsum[blockIdx.x] = sm[255];
}

__global__ void k_scan2(int* __restrict__ bsum, int nb) {
    __shared__ int sm[256];
    int v = (threadIdx.x < nb) ? bsum[threadIdx.x] : 0;
    sm[threadIdx.x] = v;
    __syncthreads();
    for (int off = 1; off < 256; off <<= 1) {
        int t = (threadIdx.x >= off) ? sm[threadIdx.x - off] : 0;
        __syncthreads();
        sm[threadIdx.x] += t;
        __syncthreads();
    }
    if (threadIdx.x < nb) bsum[threadIdx.x] = sm[threadIdx.x] - v;   // exclusive
}

__global__ void k_scan3(int* __restrict__ rp1, const int* __restrict__ bsumExcl, int N) {
    int i = blockIdx.x * 256 + threadIdx.x;
    if (i < N) rp1[i] += bsumExcl[blockIdx.x];
    if (blockIdx.x == 0 && threadIdx.x == 0) rp1[-1] = 0;            // row_ptr[0] = 0
}

__global__ void k_scatter(const int* __restrict__ src, const int* __restrict__ dst,
                          int E, int* __restrict__ cursor, int* __restrict__ csr_src) {
    for (int e = blockIdx.x * blockDim.x + threadIdx.x; e < E; e += gridDim.x * blockDim.x) {
        int d = dst[e];
        int pos = atomicAdd(&cursor[d], 1);
        csr_src[pos] = src[e];
    }
}

__global__ void k_deg(const int* __restrict__ outdeg, const int* __restrict__ indeg,
                      float* __restrict__ oi, float* __restrict__ insq, int N) {
    int i = blockIdx.x * 256 + threadIdx.x;
    if (i < N) {
        int od = outdeg[i]; if (od < 1) od = 1;
        int id = indeg[i];  if (id < 1) id = 1;
        oi[i]   = rsqrtf((float)od);
        insq[i] = sqrtf((float)id);
    }
}

// --------------------------- weight conversion ----------------------------
__global__ void k_cvt6(const float* s0, __hip_bfloat16* d0, int n0,
                       const float* s1, __hip_bfloat16* d1, int n1,
                       const float* s2, __hip_bfloat16* d2, int n2,
                       const float* s3, __hip_bfloat16* d3, int n3,
                       const float* s4, __hip_bfloat16* d4, int n4,
                       const float* s5, __hip_bfloat16* d5, int n5) {
    const float* ss; __hip_bfloat16* dd; int nn;
    switch (blockIdx.y) {
        case 0: ss = s0; dd = d0; nn = n0; break;
        case 1: ss = s1; dd = d1; nn = n1; break;
        case 2: ss = s2; dd = d2; nn = n2; break;
        case 3: ss = s3; dd = d3; nn = n3; break;
        case 4: ss = s4; dd = d4; nn = n4; break;
        default: ss = s5; dd = d5; nn = n5; break;
    }
    for (int i = blockIdx.x * blockDim.x + threadIdx.x; i < nn; i += gridDim.x * blockDim.x)
        dd[i] = __float2bfloat16(ss[i]);
}

// ----- augmented ft weights: rows 0..NF-1 = W, NF+j (j<4)=wl_h, (j<8)=wr_h,
//       NF+8..NF+15 = 0.  wl_h[k] = sum_d W[h*D+d, k]*attn_l[h*D+d] (f32). ---
__global__ void k_prepw(const float* __restrict__ W0,
                        const float* __restrict__ al0, const float* __restrict__ ar0,
                        const float* __restrict__ midW,
                        const float* __restrict__ midal, const float* __restrict__ midar,
                        __hip_bfloat16* __restrict__ Waug0,
                        __hip_bfloat16* __restrict__ midWaug) {
    const int layer = blockIdx.y;
    int NF, K, D;
    const float *W, *al, *ar;
    __hip_bfloat16* dst;
    if (layer == 0) {
        NF = 256; K = 256; D = 64;
        W = W0; al = al0; ar = ar0; dst = Waug0;
    } else {
        const int pg = layer - 1;
        NF = 128; K = 128; D = 32;
        W = midW + pg * 16384; al = midal + pg * 128; ar = midar + pg * 128;
        dst = midWaug + (size_t)pg * 144 * 128;
    }
    const int total = (NF + 16) * K;
    for (int idx = blockIdx.x * 256 + threadIdx.x; idx < total; idx += gridDim.x * 256) {
        const int col = idx / K, k = idx % K;
        float v = 0.f;
        if (col < NF) {
            v = W[(size_t)col * K + k];
        } else {
            const int j = col - NF;
            if (j < 8) {
                const int head = j & 3;
                const float* at = (j < 4) ? al : ar;
                float s = 0.f;
                for (int d = 0; d < D; ++d)
                    s += W[(size_t)(head * D + d) * K + k] * at[head * D + d];
                v = s;
            }
        }
        dst[idx] = __float2bfloat16(v);
    }
}

// ----------------- LDS-staged merged GATConv GEMM (K=128/256) -------------
// 512 thr (8 waves), BM=32. A (f32/bf16; BN-relu'd bf16) in fragment-order
// LDS. Waves col-split (ft 0-3 / res 4-7); swapped mfma -> lane stores 4
// consecutive out-cols. ft: direct ushort4 stores. res: LDS-staged coalesced
// flush (RMW-add h in place when ADDRES). Wave 0 computes aug el/er tile.
template<int K, int NF, int NR, int H, bool BN, bool ABF, bool ADDRES>
__global__ __launch_bounds__(512) void k_gatconv_lds(
    const void* __restrict__ Ain, int lda,
    const __hip_bfloat16* __restrict__ Waug,
    const __hip_bfloat16* __restrict__ Wres,
    __hip_bfloat16* __restrict__ ftb, int ldft,
    __hip_bfloat16* __restrict__ hout, int ldh, int houtoff,
    int M,
    const float* __restrict__ scale, const float* __restrict__ shift,
    const float* __restrict__ oi,
    float* __restrict__ el, float* __restrict__ er) {
    constexpr int BM = 32, KF = K / 32, NTOT = NF + NR;
    constexpr int CW = NTOT / 8, CT = CW / 16;
    constexpr int NRP = NR + 8;
    static_assert(NTOT % 8 == 0 && CW % 16 == 0, "col split");
    static_assert(NF % CW == 0, "ft/res wave boundary");
    static_assert(H == 4, "el/er float4 stores assume H==4");
    __shared__ bf16x8 ldsA[2 * KF * 64];
    __shared__ __hip_bfloat16 ores[BM][NRP];
    const int tid = threadIdx.x;
    const int wv = tid >> 6, lane = tid & 63, rf = lane & 15, kg = lane >> 4;
    const int row0 = blockIdx.x * BM;

    // ---- stage A -> (BN relu) -> bf16 -> fragment-order LDS ----
    {
        constexpr int CPR = K / 8;
        constexpr int RSTEP = 512 / CPR;
        const int c16 = tid % CPR;
        const int ec = c16 * 8;
        const int skf = c16 >> 2, skg = c16 & 3;
        float sc[8], sh[8];
        if (BN) {
            float4 s01 = *reinterpret_cast<const float4*>(scale + ec);
            float4 s23 = *reinterpret_cast<const float4*>(scale + ec + 4);
            float4 h01 = *reinterpret_cast<const float4*>(shift + ec);
            float4 h23 = *reinterpret_cast<const float4*>(shift + ec + 4);
            sc[0]=s01.x; sc[1]=s01.y; sc[2]=s01.z; sc[3]=s01.w;
            sc[4]=s23.x; sc[5]=s23.y; sc[6]=s23.z; sc[7]=s23.w;
            sh[0]=h01.x; sh[1]=h01.y; sh[2]=h01.z; sh[3]=h01.w;
            sh[4]=h23.x; sh[5]=h23.y; sh[6]=h23.z; sh[7]=h23.w;
        }
#pragma unroll
        for (int r0 = 0; r0 < BM; r0 += RSTEP) {
            const int r = r0 + tid / CPR;
            if (r < BM) {
                const int gr = row0 + r;
                bf16x8 t = zb8();
                if (gr < M) {
                    if (ABF) {
                        const __hip_bfloat16* ap =
                            (const __hip_bfloat16*)Ain + (size_t)gr * lda + ec;
                        bf16x8 raw = ldb8(ap);
                        if (BN) {
#pragma unroll
                            for (int i = 0; i < 8; ++i)
                                t[i] = (__bf16)fmaxf((float)raw[i] * sc[i] + sh[i], 0.f);
                        } else {
                            t = raw;
                        }
                    } else {
                        const float* ap = (const float*)Ain + (size_t)gr * lda + ec;
                        float4 f0 = *reinterpret_cast<const float4*>(ap);
                        float4 f1 = *reinterpret_cast<const float4*>(ap + 4);
                        float v[8] = {f0.x, f0.y, f0.z, f0.w, f1.x, f1.y, f1.z, f1.w};
#pragma unroll
                        for (int i = 0; i < 8; ++i) {
                            float u = v[i];
                            if (BN) u = fmaxf(u * sc[i] + sh[i], 0.f);
                            t[i] = (__bf16)u;
                        }
                    }
                }
                ldsA[((r >> 4) * KF + skf) * 64 + ((skg * 16 + (r & 15)) ^ skf)] = t;
            }
        }
    }
    __syncthreads();

    const bool isft = (wv * CW) < NF;
    const int colbase = isft ? wv * CW : wv * CW - NF;
    const __hip_bfloat16* __restrict__ Wb = isft ? Waug : Wres;

    bf16x8 a0[KF], a1[KF];
#pragma unroll
    for (int kf = 0; kf < KF; ++kf) {
        a0[kf] = ldsA[(0 * KF + kf) * 64 + (lane ^ kf)];
        a1[kf] = ldsA[(1 * KF + kf) * 64 + (lane ^ kf)];
    }
    const int r0g = row0 + rf;
    const int r1g = r0g + 16;

    for (int ct = 0; ct < CT; ++ct) {
        const int tcol = colbase + ct * 16;
        bf16x8 w[KF];
        const __hip_bfloat16* bp = Wb + (size_t)(tcol + rf) * K + kg * 8;
#pragma unroll
        for (int kf = 0; kf < KF; ++kf) w[kf] = ldb8(bp + kf * 32);
        f32x4 acc0 = {0.f, 0.f, 0.f, 0.f};
        f32x4 acc1 = {0.f, 0.f, 0.f, 0.f};
#pragma unroll
        for (int kf = 0; kf < KF; ++kf) {
            acc0 = __builtin_amdgcn_mfma_f32_16x16x32_bf16(w[kf], a0[kf], acc0, 0, 0, 0);
            acc1 = __builtin_amdgcn_mfma_f32_16x16x32_bf16(w[kf], a1[kf], acc1, 0, 0, 0);
        }
        const int c4 = tcol + 4 * kg;
        ushort4 q0 = {f2bu(acc0[0]), f2bu(acc0[1]), f2bu(acc0[2]), f2bu(acc0[3])};
        ushort4 q1 = {f2bu(acc1[0]), f2bu(acc1[1]), f2bu(acc1[2]), f2bu(acc1[3])};
        if (isft) {
            if (r0g < M)
                *reinterpret_cast<ushort4*>(&ftb[(size_t)r0g * ldft + c4]) = q0;
            if (r1g < M)
                *reinterpret_cast<ushort4*>(&ftb[(size_t)r1g * ldft + c4]) = q1;
        } else {
            *reinterpret_cast<ushort4*>(&ores[rf][c4]) = q0;
            *reinterpret_cast<ushort4*>(&ores[rf + 16][c4]) = q1;
        }
    }

    // ---- aug tile (el/er), wave 0 only ----
    if (wv == 0) {
        bf16x8 w[KF];
        const __hip_bfloat16* bp = Waug + (size_t)(NF + rf) * K + kg * 8;
#pragma unroll
        for (int kf = 0; kf < KF; ++kf) w[kf] = ldb8(bp + kf * 32);
        f32x4 acc0 = {0.f, 0.f, 0.f, 0.f};
        f32x4 acc1 = {0.f, 0.f, 0.f, 0.f};
#pragma unroll
        for (int kf = 0; kf < KF; ++kf) {
            acc0 = __builtin_amdgcn_mfma_f32_16x16x32_bf16(w[kf], a0[kf], acc0, 0, 0, 0);
            acc1 = __builtin_amdgcn_mfma_f32_16x16x32_bf16(w[kf], a1[kf], acc1, 0, 0, 0);
        }
        if (kg == 0) {
            if (r0g < M) {
                const float o = oi[r0g];
                float4 v = {acc0[0] * o, acc0[1] * o, acc0[2] * o, acc0[3] * o};
                *reinterpret_cast<float4*>(&el[(size_t)r0g * 4]) = v;
            }
            if (r1g < M) {
                const float o = oi[r1g];
                float4 v = {acc1[0] * o, acc1[1] * o, acc1[2] * o, acc1[3] * o};
                *reinterpret_cast<float4*>(&el[(size_t)r1g * 4]) = v;
            }
        } else if (kg == 1) {
            if (r0g < M) {
                float4 v = {acc0[0], acc0[1], acc0[2], acc0[3]};
                *reinterpret_cast<float4*>(&er[(size_t)r0g * 4]) = v;
            }
            if (r1g < M) {
                float4 v = {acc1[0], acc1[1], acc1[2], acc1[3]};
                *reinterpret_cast<float4*>(&er[(size_t)r1g * 4]) = v;
            }
        }
    }
    __syncthreads();

    // ---- coalesced flush: res (RMW-add h in place when ADDRES) ----
    {
        constexpr int CPRR = NR / 8;
        constexpr int UR = BM * CPRR;
        for (int u = tid; u < UR; u += 512) {
            const int row = u / CPRR, c8 = u % CPRR;
            const int gr = row0 + row;
            if (gr < M) {
                __hip_bfloat16* hp = hout + (size_t)gr * ldh + houtoff + c8 * 8;
                bf16x8 v = *reinterpret_cast<const bf16x8*>(&ores[row][c8 * 8]);
                if (ADDRES) {
                    bf16x8 b = ldb8(hp);
                    bf16x8 o;
#pragma unroll
                    for (int i = 0; i < 8; ++i)
                        o[i] = (__bf16)((float)v[i] + (float)b[i]);
                    *reinterpret_cast<bf16x8*>(hp) = o;
                } else {
                    *reinterpret_cast<bf16x8*>(hp) = v;
                }
            }
        }
    }
}

// -------- small merged GATConv (last layer, NOUT=40), bf16 A -------------
template<int K, int NF, int NR, int H>
__global__ __launch_bounds__(256) void k_gatconv_sm(
    const __hip_bfloat16* __restrict__ A, int lda,
    const __hip_bfloat16* __restrict__ Wft,
    const __hip_bfloat16* __restrict__ Wres,
    __hip_bfloat16* __restrict__ ftb, int ldft,
    float* __restrict__ Cres, int ldcres,
    int M,
    const float* __restrict__ scale, const float* __restrict__ shift,
    const float* __restrict__ bias,
    const float* __restrict__ attn_l, const float* __restrict__ attn_r,
    const float* __restrict__ oi,
    float* __restrict__ el, float* __restrict__ er) {
    constexpr int KF   = K / 32;
    constexpr int NCTF = (NF + 15) / 16;
    constexpr int NCTR = (NR + 15) / 16;
    constexpr int CTH  = NCTF / H;
    static_assert(NCTF % H == 0, "head tiling");
    const int wave = threadIdx.x >> 6, lane = threadIdx.x & 63;
    const int row0 = blockIdx.x * 64 + wave * 16;
    const int rf = lane & 15, kg = lane >> 4;

    bf16x8 a[KF];
    {
        const int row = row0 + rf;
        const bool rok = row < M;
#pragma unroll
        for (int kf = 0; kf < KF; ++kf) {
            const int c0 = kg * 8 + kf * 32;
            if (rok) {
                bf16x8 raw = ldb8(A + (size_t)row * lda + c0);
                float4 s01 = *reinterpret_cast<const float4*>(scale + c0);
                float4 s23 = *reinterpret_cast<const float4*>(scale + c0 + 4);
                float4 h01 = *reinterpret_cast<const float4*>(shift + c0);
                float4 h23 = *reinterpret_cast<const float4*>(shift + c0 + 4);
                float sc[8] = {s01.x,s01.y,s01.z,s01.w,s23.x,s23.y,s23.z,s23.w};
                float sh[8] = {h01.x,h01.y,h01.z,h01.w,h23.x,h23.y,h23.z,h23.w};
                bf16x8 t;
#pragma unroll
                for (int i = 0; i < 8; ++i)
                    t[i] = (__bf16)fmaxf((float)raw[i] * sc[i] + sh[i], 0.f);
                a[kf] = t;
            } else {
                a[kf] = zb8();
            }
        }
    }

    int ct = 0;
    for (int hh = 0; hh < H; ++hh) {
        float elp[4] = {0.f, 0.f, 0.f, 0.f};
        float erp[4] = {0.f, 0.f, 0.f, 0.f};
        for (int cth = 0; cth < CTH; ++cth, ++ct) {
            const int ccol = ct * 16 + rf;
            bf16x8 b[KF];
            const __hip_bfloat16* bp = Wft + (size_t)ccol * K + kg * 8;
#pragma unroll
            for (int kf = 0; kf < KF; ++kf)
                b[kf] = (ccol < NF) ? ldb8(bp + kf * 32) : zb8();
            f32x4 acc = {0.f, 0.f, 0.f, 0.f};
#pragma unroll
            for (int kf = 0; kf < KF; ++kf)
                acc = __builtin_amdgcn_mfma_f32_16x16x32_bf16(a[kf], b[kf], acc, 0, 0, 0);
            float al = 0.f, ar = 0.f;
            if (ccol < NF) { al = attn_l[ccol]; ar = attn_r[ccol]; }
            if (ccol < NF) {
#pragma unroll
                for (int r = 0; r < 4; ++r) {
                    const float v = acc[r];
                    elp[r] += v * al; erp[r] += v * ar;
                    const int row = row0 + kg * 4 + r;
                    if (row < M)
                        ftb[(size_t)row * ldft + ccol] = __float2bfloat16(v);
                }
            }
        }
#pragma unroll
        for (int off = 1; off <= 8; off <<= 1)
#pragma unroll
            for (int r = 0; r < 4; ++r) {
                elp[r] += __shfl_xor(elp[r], off);
                erp[r] += __shfl_xor(erp[r], off);
            }
        if (rf == 0) {
#pragma unroll
            for (int r = 0; r < 4; ++r) {
                const int row = row0 + kg * 4 + r;
                if (row < M) {
                    el[(size_t)row * H + hh] = oi[row] * elp[r];
                    er[(size_t)row * H + hh] = erp[r];
                }
            }
        }
    }

    for (int rt = 0; rt < NCTR; ++rt) {
        const int ccol = rt * 16 + rf;
        bf16x8 b[KF];
        const __hip_bfloat16* bp = Wres + (size_t)ccol * K + kg * 8;
#pragma unroll
        for (int kf = 0; kf < KF; ++kf)
            b[kf] = (ccol < NR) ? ldb8(bp + kf * 32) : zb8();
        f32x4 acc = {0.f, 0.f, 0.f, 0.f};
#pragma unroll
        for (int kf = 0; kf < KF; ++kf)
            acc = __builtin_amdgcn_mfma_f32_16x16x32_bf16(a[kf], b[kf], acc, 0, 0, 0);
        if (ccol < NR) {
#pragma unroll
            for (int r = 0; r < 4; ++r) {
                const int row = row0 + kg * 4 + r;
                if (row < M) {
                    float v = acc[r];
                    if (bias) v += bias[ccol];
                    Cres[(size_t)row * ldcres + ccol] = v;
                }
            }
        }
    }
}

// ------------- fused edge softmax + aggregation (+BN partials) ------------
template<int EPL>
__device__ inline void ldrow(const __hip_bfloat16* fp, float* f) {
    if constexpr (EPL == 4) {
        ushort4 q = *reinterpret_cast<const ushort4*>(fp);
        f[0] = bf2f(q.x); f[1] = bf2f(q.y); f[2] = bf2f(q.z); f[3] = bf2f(q.w);
    } else if constexpr (EPL == 2) {
        ushort2 q = *reinterpret_cast<const ushort2*>(fp);
        f[0] = bf2f(q.x); f[1] = bf2f(q.y);
    } else {
        f[0] = bf2f(*reinterpret_cast<const unsigned short*>(fp));
    }
}
__device__ inline float escore(float sc) {
    sc = sc >= 0.f ? sc : 0.2f * sc;
    sc = fminf(fmaxf(sc, -30.f), 30.f);
    return __expf(sc);
}

// 512 thr, 8 nodes/block. OBF: bf16 RMW out; BNP: emit per-block BN partials
// (deterministic slot psum[blk*2W .. +2W)): [sum(W) | sumsq(W)].
template<int H, int D, bool OBF, bool BNP>
__global__ __launch_bounds__(512) void k_agg(
    const __hip_bfloat16* __restrict__ ftb,
    const float* __restrict__ el, const float* __restrict__ er,
    const int* __restrict__ row_ptr, const int* __restrict__ csr_src,
    const float* __restrict__ oi, const float* __restrict__ insq,
    void* __restrict__ out, int ldc, int N,
    float* __restrict__ psum) {
    constexpr int W = H * D;
    constexpr int EPL = (W >= 64) ? (W / 64) : 1;
    __shared__ float smP[BNP ? 16 * W : 1];
    const int tid = threadIdx.x;
    const int lane = tid & 63, wv = tid >> 6;
    const int v = blockIdx.x * 8 + wv;
    const bool laneact = (W >= 64) || (lane < W);
    const bool act = (v < N) && laneact;
    const int col0 = lane * EPL;
    const int myh = (W >= 64) ? (col0 / D) : 0;

    float nv[EPL];
#pragma unroll
    for (int k = 0; k < EPL; ++k) nv[k] = 0.f;

    if (act) {
        const int s = row_ptr[v], e = row_ptr[v + 1];
        const float erv = er[(size_t)v * H + myh];
        float denom = 0.f;
        float acc[EPL];
#pragma unroll
        for (int k = 0; k < EPL; ++k) acc[k] = 0.f;

        int p = s;
        for (; p + 3 < e; p += 4) {
            const int u0 = csr_src[p + 0], u1 = csr_src[p + 1];
            const int u2 = csr_src[p + 2], u3 = csr_src[p + 3];
            float f0[EPL], f1[EPL], f2[EPL], f3[EPL];
            ldrow<EPL>(ftb + (size_t)u0 * W + col0, f0);
            ldrow<EPL>(ftb + (size_t)u1 * W + col0, f1);
            ldrow<EPL>(ftb + (size_t)u2 * W + col0, f2);
            ldrow<EPL>(ftb + (size_t)u3 * W + col0, f3);
            const float s0 = el[(size_t)u0 * H + myh], s1 = el[(size_t)u1 * H + myh];
            const float s2 = el[(size_t)u2 * H + myh], s3 = el[(size_t)u3 * H + myh];
            const float o0 = oi[u0], o1 = oi[u1], o2 = oi[u2], o3 = oi[u3];
            const float w0 = escore(s0 + erv), w1 = escore(s1 + erv);
            const float w2 = escore(s2 + erv), w3 = escore(s3 + erv);
            denom += (w0 + w1) + (w2 + w3);
            const float a0 = w0 * o0, a1 = w1 * o1, a2 = w2 * o2, a3 = w3 * o3;
#pragma unroll
            for (int k = 0; k < EPL; ++k)
                acc[k] += a0 * f0[k] + a1 * f1[k] + a2 * f2[k] + a3 * f3[k];
        }
        for (; p < e; ++p) {
            const int u = csr_src[p];
            float f[EPL];
            ldrow<EPL>(ftb + (size_t)u * W + col0, f);
            const float w = escore(el[(size_t)u * H + myh] + erv);
            denom += w;
            const float a = w * oi[u];
#pragma unroll
            for (int k = 0; k < EPL; ++k) acc[k] += a * f[k];
        }

        const float iv = insq[v] / fmaxf(denom, 1e-9f);
        if (OBF) {
            __hip_bfloat16* op = (__hip_bfloat16*)out + (size_t)v * ldc + col0;
            if constexpr (EPL == 4) {
                ushort4 o = *reinterpret_cast<ushort4*>(op);
                o.x = f2bu(bf2f(o.x) + iv * acc[0]);
                o.y = f2bu(bf2f(o.y) + iv * acc[1]);
                o.z = f2bu(bf2f(o.z) + iv * acc[2]);
                o.w = f2bu(bf2f(o.w) + iv * acc[3]);
                *reinterpret_cast<ushort4*>(op) = o;
                nv[0] = bf2f(o.x); nv[1] = bf2f(o.y); nv[2] = bf2f(o.z); nv[3] = bf2f(o.w);
            } else if constexpr (EPL == 2) {
                ushort2 o = *reinterpret_cast<ushort2*>(op);
                o.x = f2bu(bf2f(o.x) + iv * acc[0]);
                o.y = f2bu(bf2f(o.y) + iv * acc[1]);
                *reinterpret_cast<ushort2*>(op) = o;
                nv[0] = bf2f(o.x); nv[1] = bf2f(o.y);
            } else {
                unsigned short* up = (unsigned short*)op;
                *up = f2bu(bf2f(*up) + iv * acc[0]);
                nv[0] = bf2f(*up);
            }
        } else {
            float* op = (float*)out + (size_t)v * ldc + col0;
            if constexpr (EPL == 4) {
                float4 o = *reinterpret_cast<float4*>(op);
                o.x += iv * acc[0]; o.y += iv * acc[1]; o.z += iv * acc[2]; o.w += iv * acc[3];
                *reinterpret_cast<float4*>(op) = o;
            } else if constexpr (EPL == 2) {
                float2 o = *reinterpret_cast<float2*>(op);
                o.x += iv * acc[0]; o.y += iv * acc[1];
                *reinterpret_cast<float2*>(op) = o;
            } else {
                ((float*)out)[(size_t)v * ldc + col0] += iv * acc[0];
            }
        }
    }

    if (BNP) {
        if (laneact) {
#pragma unroll
            for (int k = 0; k < EPL; ++k) {
                smP[wv * W + col0 + k] = nv[k];
                smP[8 * W + wv * W + col0 + k] = nv[k] * nv[k];
            }
        }
        __syncthreads();
        if (tid < W) {
            float s = 0.f, q = 0.f;
#pragma unroll
            for (int w8 = 0; w8 < 8; ++w8) {
                s += smP[w8 * W + tid];
                q += smP[8 * W + w8 * W + tid];
            }
            psum[(size_t)blockIdx.x * 2 * W + tid] = s;
            psum[(size_t)blockIdx.x * 2 * W + W + tid] = q;
        }
    }
}

// --------- BN finalize from agg partials (col < split: A, else B) ---------
template<int F>
__global__ __launch_bounds__(256) void k_bn_finP(
    const float* __restrict__ psA, int wA, int offA,
    const float* __restrict__ psB, int wB, int offB, int split,
    int PRT,
    const float* __restrict__ gamma, const float* __restrict__ beta,
    float* __restrict__ scale, float* __restrict__ shift, int N) {
    const int col = blockIdx.x;
    const float* ps; int w, off;
    if (col < split) { ps = psA; w = wA; off = offA + col; }
    else             { ps = psB; w = wB; off = offB + (col - split); }
    float s = 0.f, q = 0.f;
    for (int p = threadIdx.x; p < PRT; p += 256) {
        s += ps[(size_t)p * 2 * w + off];
        q += ps[(size_t)p * 2 * w + w + off];
    }
#pragma unroll
    for (int o = 32; o; o >>= 1) {
        s += __shfl_down(s, o);
        q += __shfl_down(q, o);
    }
    __shared__ float sm[4], sm2[4];
    const int wave = threadIdx.x >> 6, lane = threadIdx.x & 63;
    if (lane == 0) { sm[wave] = s; sm2[wave] = q; }
    __syncthreads();
    if (threadIdx.x == 0) {
        s = sm[0] + sm[1] + sm[2] + sm[3];
        q = sm2[0] + sm2[1] + sm2[2] + sm2[3];
        float mu = s / N;
        float var = q / N - mu * mu;
        float isd = rsqrtf(var + 1e-5f);
        float g = gamma[col];
        scale[col] = g * isd;
        shift[col] = beta[col] - g * isd * mu;
    }
}

// ------------------------------- launcher ---------------------------------
extern "C" void kernel_launch(void* const* d_in, const int* in_sizes, int n_in,
                              void* d_out, int out_size, void* d_ws, size_t ws_size,
                              hipStream_t stream) {
    const float* x           = (const float*)d_in[0];
    const int*   src         = (const int*)d_in[1];
    const int*   dst         = (const int*)d_in[2];
    const float* W0          = (const float*)d_in[3];
    const float* attn_l0     = (const float*)d_in[4];
    const float* attn_r0     = (const float*)d_in[5];
    const float* resW0       = (const float*)d_in[6];
    const float* mid_bn_g    = (const float*)d_in[7];
    const float* mid_bn_b    = (const float*)d_in[8];
    const float* mid_W       = (const float*)d_in[9];
    const float* mid_attn_l  = (const float*)d_in[10];
    const float* mid_attn_r  = (const float*)d_in[11];
    const float* mid_resW    = (const float*)d_in[12];
    const float* norm_gamma  = (const float*)d_in[13];
    const float* norm_beta   = (const float*)d_in[14];
    const float* W_last      = (const float*)d_in[15];
    const float* attn_l_last = (const float*)d_in[16];
    const float* attn_r_last = (const float*)d_in[17];
    const float* resW_last   = (const float*)d_in[18];
    const float* bias_last   = (const float*)d_in[19];

    const int N = in_sizes[0] / IN_F;
    const int E = in_sizes[1];

    // ---- workspace carve-up (256B aligned) ----
    char* p = (char*)d_ws;
    size_t used = 0;
    auto take = [&](size_t bytes) -> char* {
        char* r = p;
        size_t adv = (bytes + 255) & ~(size_t)255;
        p += adv; used += adv;
        return r;
    };
    const int NBb = (N + 7) / 8;                    // k_agg blocks (8 nodes each)
    __hip_bfloat16* h       = (__hip_bfloat16*)take((size_t)N * HIDW * 2);
    __hip_bfloat16* ftb     = (__hip_bfloat16*)take((size_t)N * HIDW * 2);
    float*          el      = (float*)take((size_t)N * 4 * 4);
    float*          er      = (float*)take((size_t)N * 4 * 4);
    float*          oi      = (float*)take((size_t)N * 4);
    float*          insq    = (float*)take((size_t)N * 4);
    int*            indeg   = (int*)take((size_t)N * 4);
    int*            outdeg  = (int*)take((size_t)N * 4);
    int*            row_ptr = (int*)take((size_t)(N + 1) * 4);
    int*            cursor  = (int*)take((size_t)N * 4);
    int*            csr_src = (int*)take((size_t)E * 4);
    int*            bsum    = (int*)take(256 * 4);
    float*          psX     = (float*)take((size_t)NBb * 512 * 4);   // W=256 slots
    float*          psY     = (float*)take((size_t)NBb * 256 * 4);   // W=128 slots
    float*          psZ     = (float*)take((size_t)NBb * 256 * 4);
    float*          scale   = (float*)take(1024);
    float*          shift   = (float*)take(1024);
    __hip_bfloat16* Waug0     = (__hip_bfloat16*)take((size_t)272 * 256 * 2);
    __hip_bfloat16* midWaug   = (__hip_bfloat16*)take((size_t)4 * 144 * 128 * 2);
    __hip_bfloat16* resW0bf   = (__hip_bfloat16*)take(65536 * 2);
    __hip_bfloat16* midresWbf = (__hip_bfloat16*)take(65536 * 2);
    __hip_bfloat16* Wlastbf   = (__hip_bfloat16*)take(10240 * 2);
    __hip_bfloat16* resWlastbf= (__hip_bfloat16*)take(10240 * 2);
    if (used > ws_size) return;   // out of workspace: leave output poisoned (visible failure)

    const int nbN = (N + 255) / 256;
    const int GWB = (N + 31) / 32;              // 32 rows/block (8 waves, col split)
    const int GWS = (N + 63) / 64;              // small kernel: 64 rows/block

    // ---- graph prep ----
    hipMemsetAsync(indeg, 0, (size_t)N * 4, stream);
    hipMemsetAsync(outdeg, 0, (size_t)N * 4, stream);
    k_hist<<<1024, 256, 0, stream>>>(src, dst, E, outdeg, indeg);
    k_scan1<<<nbN, 256, 0, stream>>>(indeg, N, row_ptr + 1, bsum);
    k_scan2<<<1, 256, 0, stream>>>(bsum, nbN);
    k_scan3<<<nbN, 256, 0, stream>>>(row_ptr + 1, bsum, N);
    hipMemcpyAsync(cursor, row_ptr, (size_t)N * 4, hipMemcpyDeviceToDevice, stream);
    k_scatter<<<1024, 256, 0, stream>>>(src, dst, E, cursor, csr_src);
    k_deg<<<nbN, 256, 0, stream>>>(outdeg, indeg, oi, insq, N);

    // ---- weight conversion + augmentation ----
    k_cvt6<<<dim3(64, 4), 256, 0, stream>>>(resW0, resW0bf, 65536,
                                            mid_resW, midresWbf, 65536,
                                            W_last, Wlastbf, 10240,
                                            resW_last, resWlastbf, 10240,
                                            nullptr, nullptr, 0,
                                            nullptr, nullptr, 0);
    k_prepw<<<dim3(96, 5), 256, 0, stream>>>(W0, attn_l0, attn_r0,
                                             mid_W, mid_attn_l, mid_attn_r,
                                             Waug0, midWaug);

    // ---- layer 0: GATConv(256 -> 4x64), A = x (f32, no BN) ----
    k_gatconv_lds<256, 256, 256, 4, false, false, false><<<GWB, 512, 0, stream>>>(
        x, 256, Waug0, resW0bf, ftb, 256, h, 256, 0, N,
        nullptr, nullptr, oi, el, er);
    k_agg<4, 64, true, true><<<NBb, 512, 0, stream>>>(ftb, el, er, row_ptr, csr_src,
                                                      oi, insq, h, 256, N, psX);

    // ---- reversible middle layers ----
    // BN source mapping: mid00<-psX(off128), mid01<-psX(off0 W128),
    // mid10<-psX(off0), mid11<-psY(off0); final<-psY(cols0-127)+psZ(128-255).
    float* midps[4]    = {psX, psX, psY, psZ};   // where each mid agg WRITES
    for (int l = 0; l < 2; ++l) {
        for (int g = 0; g < 2; ++g) {
            const int inoff  = (g == 0) ? 128 : 0;
            const int outoff = (g == 0) ? 0 : 128;
            const int pg = l * 2 + g;
            // BN finalize for this layer's input
            if (pg == 0)
                k_bn_finP<128><<<128, 256, 0, stream>>>(psX, 256, 128,
                                                        nullptr, 0, 0, 128, NBb,
                                                        mid_bn_g, mid_bn_b,
                                                        scale, shift, N);
            else
                k_bn_finP<128><<<128, 256, 0, stream>>>(midps[pg - 1], 128, 0,
                                                        nullptr, 0, 0, 128, NBb,
                                                        mid_bn_g + pg * 128,
                                                        mid_bn_b + pg * 128,
                                                        scale, shift, N);
            k_gatconv_lds<128, 128, 128, 4, true, true, true><<<GWB, 512, 0, stream>>>(
                h + inoff, 256, midWaug + (size_t)pg * 144 * 128, midresWbf + pg * 16384,
                ftb, 128, h, 256, outoff, N,
                scale, shift, oi, el, er);
            k_agg<4, 32, true, true><<<NBb, 512, 0, stream>>>(ftb, el, er, row_ptr, csr_src,
                                                              oi, insq, h + outoff, 256, N,
                                                              midps[pg]);
        }
    }

    // ---- final norm (from mid10/mid11 agg partials) + last GATConv ----
    k_bn_finP<256><<<256, 256, 0, stream>>>(psY, 128, 0, psZ, 128, 0, 128, NBb,
                                            norm_gamma, norm_beta, scale, shift, N);
    k_gatconv_sm<256, 40, 40, 1><<<GWS, 256, 0, stream>>>(
        h, 256, Wlastbf, resWlastbf, ftb, 40, (float*)d_out, 40, N,
        scale, shift, bias_last,
        attn_l_last, attn_r_last, oi, el, er);
    k_agg<1, 40, false, false><<<NBb, 512, 0, stream>>>(ftb, el, er, row_ptr, csr_src,
                                                        oi, insq, (float*)d_out, 40, N,
                                                        nullptr);
}

// Round 14
// 558.357 us; speedup vs baseline: 1.0630x; 1.0630x over previous
//
#include <hip/hip_runtime.h>
#include <hip/hip_bf16.h>

// ---------------------------------------------------------------------------
// RevGAT forward on MI355X.
// R2-R4: BN widened, k_agg single-pass, big fusion (706us).
// R5/R6/R10: col-split replication / no-LDS / 4-wave REGRESSED.
// R7-R9: LDS 8-wave col-split, swapped MFMA, el/er aug cols (581us; GEMM
//        best-ever 61-66us at BM=64/782 blocks, B-in-regs ct-outer loop).
// R11/R12: BM=32 queue + bf16 h + coalesced flush (559us best total).
// R13: BN-fused 512-thr agg REGRESSED (594us) -> reverted.
// R14: recombination of measured bests: R9 GEMM geometry (BM=64, ct-outer,
//      B in regs over 4 row-frags) with bf16 h I/O + R12 launcher
//      (separate bf16 bn_part, 256-thr agg).
// ---------------------------------------------------------------------------

#define IN_F   256
#define HIDW   256          // HEADS*HID
#define CLS    40

typedef __attribute__((ext_vector_type(8))) __bf16 bf16x8;
typedef __attribute__((ext_vector_type(4))) float  f32x4;

__device__ inline bf16x8 zb8() {
    bf16x8 v;
#pragma unroll
    for (int i = 0; i < 8; ++i) v[i] = (__bf16)0.f;
    return v;
}
__device__ inline bf16x8 ldb8(const __hip_bfloat16* p) {
    return *reinterpret_cast<const bf16x8*>(p);
}
__device__ inline float bf2f(unsigned short u) {
    union { unsigned int i; float f; } c;
    c.i = ((unsigned int)u) << 16;
    return c.f;
}
__device__ inline unsigned short f2bu(float f) {
    __hip_bfloat16 t = __float2bfloat16(f);
    union { __hip_bfloat16 b; unsigned short u; } c;
    c.b = t;
    return c.u;
}

// ------------------------------ graph prep --------------------------------
__global__ void k_hist(const int* __restrict__ src, const int* __restrict__ dst,
                       int E, int* __restrict__ outdeg, int* __restrict__ indeg) {
    for (int e = blockIdx.x * blockDim.x + threadIdx.x; e < E; e += gridDim.x * blockDim.x) {
        atomicAdd(&outdeg[src[e]], 1);
        atomicAdd(&indeg[dst[e]], 1);
    }
}

__global__ void k_scan1(const int* __restrict__ cnt, int N, int* __restrict__ rp1,
                        int* __restrict__ bsum) {
    __shared__ int sm[256];
    int i = blockIdx.x * 256 + threadIdx.x;
    int v = (i < N) ? cnt[i] : 0;
    sm[threadIdx.x] = v;
    __syncthreads();
    for (int off = 1; off < 256; off <<= 1) {
        int t = (threadIdx.x >= off) ? sm[threadIdx.x - off] : 0;
        __syncthreads();
        sm[threadIdx.x] += t;
        __syncthreads();
    }
    if (i < N) rp1[i] = sm[threadIdx.x];                  // inclusive within block
    if (threadIdx.x == 255) bsum[blockIdx.x] = sm[255];
}

__global__ void k_scan2(int* __restrict__ bsum, int nb) {
    __shared__ int sm[256];
    int v = (threadIdx.x < nb) ? bsum[threadIdx.x] : 0;
    sm[threadIdx.x] = v;
    __syncthreads();
    for (int off = 1; off < 256; off <<= 1) {
        int t = (threadIdx.x >= off) ? sm[threadIdx.x - off] : 0;
        __syncthreads();
        sm[threadIdx.x] += t;
        __syncthreads();
    }
    if (threadIdx.x < nb) bsum[threadIdx.x] = sm[threadIdx.x] - v;   // exclusive
}

__global__ void k_scan3(int* __restrict__ rp1, const int* __restrict__ bsumExcl, int N) {
    int i = blockIdx.x * 256 + threadIdx.x;
    if (i < N) rp1[i] += bsumExcl[blockIdx.x];
    if (blockIdx.x == 0 && threadIdx.x == 0) rp1[-1] = 0;            // row_ptr[0] = 0
}

__global__ void k_scatter(const int* __restrict__ src, const int* __restrict__ dst,
                          int E, int* __restrict__ cursor, int* __restrict__ csr_src) {
    for (int e = blockIdx.x * blockDim.x + threadIdx.x; e < E; e += gridDim.x * blockDim.x) {
        int d = dst[e];
        int pos = atomicAdd(&cursor[d], 1);
        csr_src[pos] = src[e];
    }
}

__global__ void k_deg(const int* __restrict__ outdeg, const int* __restrict__ indeg,
                      float* __restrict__ oi, float* __restrict__ insq, int N) {
    int i = blockIdx.x * 256 + threadIdx.x;
    if (i < N) {
        int od = outdeg[i]; if (od < 1) od = 1;
        int id = indeg[i];  if (id < 1) id = 1;
        oi[i]   = rsqrtf((float)od);
        insq[i] = sqrtf((float)id);
    }
}

// --------------------------- weight conversion ----------------------------
__global__ void k_cvt6(const float* s0, __hip_bfloat16* d0, int n0,
                       const float* s1, __hip_bfloat16* d1, int n1,
                       const float* s2, __hip_bfloat16* d2, int n2,
                       const float* s3, __hip_bfloat16* d3, int n3,
                       const float* s4, __hip_bfloat16* d4, int n4,
                       const float* s5, __hip_bfloat16* d5, int n5) {
    const float* ss; __hip_bfloat16* dd; int nn;
    switch (blockIdx.y) {
        case 0: ss = s0; dd = d0; nn = n0; break;
        case 1: ss = s1; dd = d1; nn = n1; break;
        case 2: ss = s2; dd = d2; nn = n2; break;
        case 3: ss = s3; dd = d3; nn = n3; break;
        case 4: ss = s4; dd = d4; nn = n4; break;
        default: ss = s5; dd = d5; nn = n5; break;
    }
    for (int i = blockIdx.x * blockDim.x + threadIdx.x; i < nn; i += gridDim.x * blockDim.x)
        dd[i] = __float2bfloat16(ss[i]);
}

// ----- augmented ft weights: rows 0..NF-1 = W, NF+j (j<4)=wl_h, (j<8)=wr_h,
//       NF+8..NF+15 = 0.  wl_h[k] = sum_d W[h*D+d, k]*attn_l[h*D+d] (f32). ---
__global__ void k_prepw(const float* __restrict__ W0,
                        const float* __restrict__ al0, const float* __restrict__ ar0,
                        const float* __restrict__ midW,
                        const float* __restrict__ midal, const float* __restrict__ midar,
                        __hip_bfloat16* __restrict__ Waug0,
                        __hip_bfloat16* __restrict__ midWaug) {
    const int layer = blockIdx.y;
    int NF, K, D;
    const float *W, *al, *ar;
    __hip_bfloat16* dst;
    if (layer == 0) {
        NF = 256; K = 256; D = 64;
        W = W0; al = al0; ar = ar0; dst = Waug0;
    } else {
        const int pg = layer - 1;
        NF = 128; K = 128; D = 32;
        W = midW + pg * 16384; al = midal + pg * 128; ar = midar + pg * 128;
        dst = midWaug + (size_t)pg * 144 * 128;
    }
    const int total = (NF + 16) * K;
    for (int idx = blockIdx.x * 256 + threadIdx.x; idx < total; idx += gridDim.x * 256) {
        const int col = idx / K, k = idx % K;
        float v = 0.f;
        if (col < NF) {
            v = W[(size_t)col * K + k];
        } else {
            const int j = col - NF;
            if (j < 8) {
                const int head = j & 3;
                const float* at = (j < 4) ? al : ar;
                float s = 0.f;
                for (int d = 0; d < D; ++d)
                    s += W[(size_t)(head * D + d) * K + k] * at[head * D + d];
                v = s;
            }
        }
        dst[idx] = __float2bfloat16(v);
    }
}

// ----------------- LDS-staged merged GATConv GEMM (K=128/256) -------------
// R9 geometry: 512 thr (8 waves), BM=64, fragment-order LDS. Waves col-split
// (ft 0-3 / res 4-7). ct-outer: B tile held in regs across 4 row-fragments.
// Swapped mfma: lane stores 4 consecutive out-cols -> ushort4 stores.
// res path: bf16 h, optional RMW-add (in-place). Wave 0: aug el/er tile.
template<int K, int NF, int NR, int H, bool BN, bool ABF, bool ADDRES>
__global__ __launch_bounds__(512) void k_gatconv_lds(
    const void* __restrict__ Ain, int lda,
    const __hip_bfloat16* __restrict__ Waug,
    const __hip_bfloat16* __restrict__ Wres,
    __hip_bfloat16* __restrict__ ftb, int ldft,
    __hip_bfloat16* __restrict__ hout, int ldh, int houtoff,
    int M,
    const float* __restrict__ scale, const float* __restrict__ shift,
    const float* __restrict__ oi,
    float* __restrict__ el, float* __restrict__ er) {
    constexpr int BM = 64, KF = K / 32, NTOT = NF + NR;
    constexpr int CW = NTOT / 8, CT = CW / 16;
    constexpr int NRT = BM / 16;
    static_assert(NTOT % 8 == 0 && CW % 16 == 0, "col split");
    static_assert(NF % CW == 0, "ft/res wave boundary");
    static_assert(H == 4, "el/er float4 stores assume H==4");
    __shared__ bf16x8 ldsA[NRT * KF * 64];
    const int tid = threadIdx.x;
    const int wv = tid >> 6, lane = tid & 63, rf = lane & 15, kg = lane >> 4;
    const int row0 = blockIdx.x * BM;

    // ---- stage A -> (BN relu) -> bf16 -> fragment-order LDS ----
    {
        constexpr int CPR = K / 8;            // 8-elem chunks per row
        constexpr int RSTEP = 512 / CPR;      // rows per pass
        const int c16 = tid % CPR;
        const int ec = c16 * 8;
        const int skf = c16 >> 2, skg = c16 & 3;
        float sc[8], sh[8];
        if (BN) {
            float4 s01 = *reinterpret_cast<const float4*>(scale + ec);
            float4 s23 = *reinterpret_cast<const float4*>(scale + ec + 4);
            float4 h01 = *reinterpret_cast<const float4*>(shift + ec);
            float4 h23 = *reinterpret_cast<const float4*>(shift + ec + 4);
            sc[0]=s01.x; sc[1]=s01.y; sc[2]=s01.z; sc[3]=s01.w;
            sc[4]=s23.x; sc[5]=s23.y; sc[6]=s23.z; sc[7]=s23.w;
            sh[0]=h01.x; sh[1]=h01.y; sh[2]=h01.z; sh[3]=h01.w;
            sh[4]=h23.x; sh[5]=h23.y; sh[6]=h23.z; sh[7]=h23.w;
        }
#pragma unroll
        for (int r0 = 0; r0 < BM; r0 += RSTEP) {
            const int r = r0 + tid / CPR;
            if (r < BM) {
                const int gr = row0 + r;
                bf16x8 t = zb8();
                if (gr < M) {
                    if (ABF) {
                        const __hip_bfloat16* ap =
                            (const __hip_bfloat16*)Ain + (size_t)gr * lda + ec;
                        bf16x8 raw = ldb8(ap);
                        if (BN) {
#pragma unroll
                            for (int i = 0; i < 8; ++i)
                                t[i] = (__bf16)fmaxf((float)raw[i] * sc[i] + sh[i], 0.f);
                        } else {
                            t = raw;
                        }
                    } else {
                        const float* ap = (const float*)Ain + (size_t)gr * lda + ec;
                        float4 f0 = *reinterpret_cast<const float4*>(ap);
                        float4 f1 = *reinterpret_cast<const float4*>(ap + 4);
                        float v[8] = {f0.x, f0.y, f0.z, f0.w, f1.x, f1.y, f1.z, f1.w};
#pragma unroll
                        for (int i = 0; i < 8; ++i) {
                            float u = v[i];
                            if (BN) u = fmaxf(u * sc[i] + sh[i], 0.f);
                            t[i] = (__bf16)u;
                        }
                    }
                }
                ldsA[((r >> 4) * KF + skf) * 64 + ((skg * 16 + (r & 15)) ^ skf)] = t;
            }
        }
    }
    __syncthreads();

    const bool isft = (wv * CW) < NF;
    const int colbase = isft ? wv * CW : wv * CW - NF;
    const __hip_bfloat16* __restrict__ Wb = isft ? Waug : Wres;

    for (int ct = 0; ct < CT; ++ct) {
        const int tcol = colbase + ct * 16;
        bf16x8 w[KF];
        const __hip_bfloat16* bp = Wb + (size_t)(tcol + rf) * K + kg * 8;
#pragma unroll
        for (int kf = 0; kf < KF; ++kf) w[kf] = ldb8(bp + kf * 32);
#pragma unroll
        for (int rtp = 0; rtp < NRT / 2; ++rtp) {
            f32x4 acc0 = {0.f, 0.f, 0.f, 0.f};
            f32x4 acc1 = {0.f, 0.f, 0.f, 0.f};
#pragma unroll
            for (int kf = 0; kf < KF; ++kf) {
                const bf16x8 a0 = ldsA[((2 * rtp) * KF + kf) * 64 + (lane ^ kf)];
                const bf16x8 a1 = ldsA[((2 * rtp + 1) * KF + kf) * 64 + (lane ^ kf)];
                acc0 = __builtin_amdgcn_mfma_f32_16x16x32_bf16(w[kf], a0, acc0, 0, 0, 0);
                acc1 = __builtin_amdgcn_mfma_f32_16x16x32_bf16(w[kf], a1, acc1, 0, 0, 0);
            }
            // swapped D: lane holds out row rf(+16*rt), cols tcol+4kg..+3
            const int r0g = row0 + 2 * rtp * 16 + rf;
            const int r1g = r0g + 16;
            const int c4 = tcol + 4 * kg;
            ushort4 q0 = {f2bu(acc0[0]), f2bu(acc0[1]), f2bu(acc0[2]), f2bu(acc0[3])};
            ushort4 q1 = {f2bu(acc1[0]), f2bu(acc1[1]), f2bu(acc1[2]), f2bu(acc1[3])};
            if (isft) {
                if (r0g < M)
                    *reinterpret_cast<ushort4*>(&ftb[(size_t)r0g * ldft + c4]) = q0;
                if (r1g < M)
                    *reinterpret_cast<ushort4*>(&ftb[(size_t)r1g * ldft + c4]) = q1;
            } else {
                if (r0g < M) {
                    __hip_bfloat16* hp = hout + (size_t)r0g * ldh + houtoff + c4;
                    if (ADDRES) {
                        ushort4 cur = *reinterpret_cast<ushort4*>(hp);
                        q0.x = f2bu(bf2f(cur.x) + acc0[0]);
                        q0.y = f2bu(bf2f(cur.y) + acc0[1]);
                        q0.z = f2bu(bf2f(cur.z) + acc0[2]);
                        q0.w = f2bu(bf2f(cur.w) + acc0[3]);
                    }
                    *reinterpret_cast<ushort4*>(hp) = q0;
                }
                if (r1g < M) {
                    __hip_bfloat16* hp = hout + (size_t)r1g * ldh + houtoff + c4;
                    if (ADDRES) {
                        ushort4 cur = *reinterpret_cast<ushort4*>(hp);
                        q1.x = f2bu(bf2f(cur.x) + acc1[0]);
                        q1.y = f2bu(bf2f(cur.y) + acc1[1]);
                        q1.z = f2bu(bf2f(cur.z) + acc1[2]);
                        q1.w = f2bu(bf2f(cur.w) + acc1[3]);
                    }
                    *reinterpret_cast<ushort4*>(hp) = q1;
                }
            }
        }
    }

    // ---- aug tile (el/er), wave 0 only: cols NF..NF+15 of Waug ----
    if (wv == 0) {
        bf16x8 w[KF];
        const __hip_bfloat16* bp = Waug + (size_t)(NF + rf) * K + kg * 8;
#pragma unroll
        for (int kf = 0; kf < KF; ++kf) w[kf] = ldb8(bp + kf * 32);
#pragma unroll
        for (int rtp = 0; rtp < NRT / 2; ++rtp) {
            f32x4 acc0 = {0.f, 0.f, 0.f, 0.f};
            f32x4 acc1 = {0.f, 0.f, 0.f, 0.f};
#pragma unroll
            for (int kf = 0; kf < KF; ++kf) {
                const bf16x8 a0 = ldsA[((2 * rtp) * KF + kf) * 64 + (lane ^ kf)];
                const bf16x8 a1 = ldsA[((2 * rtp + 1) * KF + kf) * 64 + (lane ^ kf)];
                acc0 = __builtin_amdgcn_mfma_f32_16x16x32_bf16(w[kf], a0, acc0, 0, 0, 0);
                acc1 = __builtin_amdgcn_mfma_f32_16x16x32_bf16(w[kf], a1, acc1, 0, 0, 0);
            }
            const int r0g = row0 + 2 * rtp * 16 + rf;
            const int r1g = r0g + 16;
            if (kg == 0) {        // el heads 0..3 (scaled by oi)
                if (r0g < M) {
                    const float o = oi[r0g];
                    float4 v = {acc0[0] * o, acc0[1] * o, acc0[2] * o, acc0[3] * o};
                    *reinterpret_cast<float4*>(&el[(size_t)r0g * 4]) = v;
                }
                if (r1g < M) {
                    const float o = oi[r1g];
                    float4 v = {acc1[0] * o, acc1[1] * o, acc1[2] * o, acc1[3] * o};
                    *reinterpret_cast<float4*>(&el[(size_t)r1g * 4]) = v;
                }
            } else if (kg == 1) { // er heads 0..3
                if (r0g < M) {
                    float4 v = {acc0[0], acc0[1], acc0[2], acc0[3]};
                    *reinterpret_cast<float4*>(&er[(size_t)r0g * 4]) = v;
                }
                if (r1g < M) {
                    float4 v = {acc1[0], acc1[1], acc1[2], acc1[3]};
                    *reinterpret_cast<float4*>(&er[(size_t)r1g * 4]) = v;
                }
            }
        }
    }
}

// -------- small merged GATConv (last layer, NOUT=40), bf16 A -------------
template<int K, int NF, int NR, int H>
__global__ __launch_bounds__(256) void k_gatconv_sm(
    const __hip_bfloat16* __restrict__ A, int lda,
    const __hip_bfloat16* __restrict__ Wft,
    const __hip_bfloat16* __restrict__ Wres,
    __hip_bfloat16* __restrict__ ftb, int ldft,
    float* __restrict__ Cres, int ldcres,
    int M,
    const float* __restrict__ scale, const float* __restrict__ shift,
    const float* __restrict__ bias,
    const float* __restrict__ attn_l, const float* __restrict__ attn_r,
    const float* __restrict__ oi,
    float* __restrict__ el, float* __restrict__ er) {
    constexpr int KF   = K / 32;
    constexpr int NCTF = (NF + 15) / 16;
    constexpr int NCTR = (NR + 15) / 16;
    constexpr int CTH  = NCTF / H;
    static_assert(NCTF % H == 0, "head tiling");
    const int wave = threadIdx.x >> 6, lane = threadIdx.x & 63;
    const int row0 = blockIdx.x * 64 + wave * 16;
    const int rf = lane & 15, kg = lane >> 4;

    bf16x8 a[KF];
    {
        const int row = row0 + rf;
        const bool rok = row < M;
#pragma unroll
        for (int kf = 0; kf < KF; ++kf) {
            const int c0 = kg * 8 + kf * 32;
            if (rok) {
                bf16x8 raw = ldb8(A + (size_t)row * lda + c0);
                float4 s01 = *reinterpret_cast<const float4*>(scale + c0);
                float4 s23 = *reinterpret_cast<const float4*>(scale + c0 + 4);
                float4 h01 = *reinterpret_cast<const float4*>(shift + c0);
                float4 h23 = *reinterpret_cast<const float4*>(shift + c0 + 4);
                float sc[8] = {s01.x,s01.y,s01.z,s01.w,s23.x,s23.y,s23.z,s23.w};
                float sh[8] = {h01.x,h01.y,h01.z,h01.w,h23.x,h23.y,h23.z,h23.w};
                bf16x8 t;
#pragma unroll
                for (int i = 0; i < 8; ++i)
                    t[i] = (__bf16)fmaxf((float)raw[i] * sc[i] + sh[i], 0.f);
                a[kf] = t;
            } else {
                a[kf] = zb8();
            }
        }
    }

    int ct = 0;
    for (int hh = 0; hh < H; ++hh) {
        float elp[4] = {0.f, 0.f, 0.f, 0.f};
        float erp[4] = {0.f, 0.f, 0.f, 0.f};
        for (int cth = 0; cth < CTH; ++cth, ++ct) {
            const int ccol = ct * 16 + rf;
            bf16x8 b[KF];
            const __hip_bfloat16* bp = Wft + (size_t)ccol * K + kg * 8;
#pragma unroll
            for (int kf = 0; kf < KF; ++kf)
                b[kf] = (ccol < NF) ? ldb8(bp + kf * 32) : zb8();
            f32x4 acc = {0.f, 0.f, 0.f, 0.f};
#pragma unroll
            for (int kf = 0; kf < KF; ++kf)
                acc = __builtin_amdgcn_mfma_f32_16x16x32_bf16(a[kf], b[kf], acc, 0, 0, 0);
            float al = 0.f, ar = 0.f;
            if (ccol < NF) { al = attn_l[ccol]; ar = attn_r[ccol]; }
            if (ccol < NF) {
#pragma unroll
                for (int r = 0; r < 4; ++r) {
                    const float v = acc[r];
                    elp[r] += v * al; erp[r] += v * ar;
                    const int row = row0 + kg * 4 + r;
                    if (row < M)
                        ftb[(size_t)row * ldft + ccol] = __float2bfloat16(v);
                }
            }
        }
#pragma unroll
        for (int off = 1; off <= 8; off <<= 1)
#pragma unroll
            for (int r = 0; r < 4; ++r) {
                elp[r] += __shfl_xor(elp[r], off);
                erp[r] += __shfl_xor(erp[r], off);
            }
        if (rf == 0) {
#pragma unroll
            for (int r = 0; r < 4; ++r) {
                const int row = row0 + kg * 4 + r;
                if (row < M) {
                    el[(size_t)row * H + hh] = oi[row] * elp[r];
                    er[(size_t)row * H + hh] = erp[r];
                }
            }
        }
    }

    for (int rt = 0; rt < NCTR; ++rt) {
        const int ccol = rt * 16 + rf;
        bf16x8 b[KF];
        const __hip_bfloat16* bp = Wres + (size_t)ccol * K + kg * 8;
#pragma unroll
        for (int kf = 0; kf < KF; ++kf)
            b[kf] = (ccol < NR) ? ldb8(bp + kf * 32) : zb8();
        f32x4 acc = {0.f, 0.f, 0.f, 0.f};
#pragma unroll
        for (int kf = 0; kf < KF; ++kf)
            acc = __builtin_amdgcn_mfma_f32_16x16x32_bf16(a[kf], b[kf], acc, 0, 0, 0);
        if (ccol < NR) {
#pragma unroll
            for (int r = 0; r < 4; ++r) {
                const int row = row0 + kg * 4 + r;
                if (row < M) {
                    float v = acc[r];
                    if (bias) v += bias[ccol];
                    Cres[(size_t)row * ldcres + ccol] = v;
                }
            }
        }
    }
}

// ------------- fused edge softmax + message aggregation (per dst) ---------
template<int EPL>
__device__ inline void ldrow(const __hip_bfloat16* fp, float* f) {
    if constexpr (EPL == 4) {
        ushort4 q = *reinterpret_cast<const ushort4*>(fp);
        f[0] = bf2f(q.x); f[1] = bf2f(q.y); f[2] = bf2f(q.z); f[3] = bf2f(q.w);
    } else if constexpr (EPL == 2) {
        ushort2 q = *reinterpret_cast<const ushort2*>(fp);
        f[0] = bf2f(q.x); f[1] = bf2f(q.y);
    } else {
        f[0] = bf2f(*reinterpret_cast<const unsigned short*>(fp));
    }
}
__device__ inline float escore(float sc) {
    sc = sc >= 0.f ? sc : 0.2f * sc;
    sc = fminf(fmaxf(sc, -30.f), 30.f);
    return __expf(sc);
}

// OBF: out is bf16 (RMW); else f32 (RMW).
template<int H, int D, bool OBF>
__global__ __launch_bounds__(256) void k_agg(
    const __hip_bfloat16* __restrict__ ftb,
    const float* __restrict__ el, const float* __restrict__ er,
    const int* __restrict__ row_ptr, const int* __restrict__ csr_src,
    const float* __restrict__ oi, const float* __restrict__ insq,
    void* __restrict__ out, int ldc, int N) {
    constexpr int W = H * D;
    constexpr int EPL = (W >= 64) ? (W / 64) : 1;
    const int lane = threadIdx.x & 63;
    const int v = blockIdx.x * 4 + (threadIdx.x >> 6);
    if (v >= N) return;
    if (W < 64 && lane >= W) return;
    const int col0 = lane * EPL;
    const int myh = (W >= 64) ? (col0 / D) : 0;
    const int s = row_ptr[v], e = row_ptr[v + 1];
    const float erv = er[(size_t)v * H + myh];

    float denom = 0.f;
    float acc[EPL];
#pragma unroll
    for (int k = 0; k < EPL; ++k) acc[k] = 0.f;

    int p = s;
    for (; p + 3 < e; p += 4) {
        const int u0 = csr_src[p + 0], u1 = csr_src[p + 1];
        const int u2 = csr_src[p + 2], u3 = csr_src[p + 3];
        float f0[EPL], f1[EPL], f2[EPL], f3[EPL];
        ldrow<EPL>(ftb + (size_t)u0 * W + col0, f0);
        ldrow<EPL>(ftb + (size_t)u1 * W + col0, f1);
        ldrow<EPL>(ftb + (size_t)u2 * W + col0, f2);
        ldrow<EPL>(ftb + (size_t)u3 * W + col0, f3);
        const float s0 = el[(size_t)u0 * H + myh], s1 = el[(size_t)u1 * H + myh];
        const float s2 = el[(size_t)u2 * H + myh], s3 = el[(size_t)u3 * H + myh];
        const float o0 = oi[u0], o1 = oi[u1], o2 = oi[u2], o3 = oi[u3];
        const float w0 = escore(s0 + erv), w1 = escore(s1 + erv);
        const float w2 = escore(s2 + erv), w3 = escore(s3 + erv);
        denom += (w0 + w1) + (w2 + w3);
        const float a0 = w0 * o0, a1 = w1 * o1, a2 = w2 * o2, a3 = w3 * o3;
#pragma unroll
        for (int k = 0; k < EPL; ++k)
            acc[k] += a0 * f0[k] + a1 * f1[k] + a2 * f2[k] + a3 * f3[k];
    }
    for (; p < e; ++p) {
        const int u = csr_src[p];
        float f[EPL];
        ldrow<EPL>(ftb + (size_t)u * W + col0, f);
        const float w = escore(el[(size_t)u * H + myh] + erv);
        denom += w;
        const float a = w * oi[u];
#pragma unroll
        for (int k = 0; k < EPL; ++k) acc[k] += a * f[k];
    }

    const float iv = insq[v] / fmaxf(denom, 1e-9f);
    if (OBF) {
        __hip_bfloat16* op = (__hip_bfloat16*)out + (size_t)v * ldc + col0;
        if constexpr (EPL == 4) {
            ushort4 o = *reinterpret_cast<ushort4*>(op);
            o.x = f2bu(bf2f(o.x) + iv * acc[0]);
            o.y = f2bu(bf2f(o.y) + iv * acc[1]);
            o.z = f2bu(bf2f(o.z) + iv * acc[2]);
            o.w = f2bu(bf2f(o.w) + iv * acc[3]);
            *reinterpret_cast<ushort4*>(op) = o;
        } else if constexpr (EPL == 2) {
            ushort2 o = *reinterpret_cast<ushort2*>(op);
            o.x = f2bu(bf2f(o.x) + iv * acc[0]);
            o.y = f2bu(bf2f(o.y) + iv * acc[1]);
            *reinterpret_cast<ushort2*>(op) = o;
        } else {
            unsigned short* up = (unsigned short*)op;
            *up = f2bu(bf2f(*up) + iv * acc[0]);
        }
    } else {
        float* op = (float*)out + (size_t)v * ldc + col0;
        if constexpr (EPL == 4) {
            float4 o = *reinterpret_cast<float4*>(op);
            o.x += iv * acc[0]; o.y += iv * acc[1]; o.z += iv * acc[2]; o.w += iv * acc[3];
            *reinterpret_cast<float4*>(op) = o;
        } else if constexpr (EPL == 2) {
            float2 o = *reinterpret_cast<float2*>(op);
            o.x += iv * acc[0]; o.y += iv * acc[1];
            *reinterpret_cast<float2*>(op) = o;
        } else {
            op[0] += iv * acc[0];
        }
    }
}

// ------------------------------ batch norm (bf16 input) -------------------
template<int F>
__global__ __launch_bounds__(256) void k_bn_part(const __hip_bfloat16* __restrict__ in,
                                                 int ldin, int N,
                                                 float* __restrict__ psum,
                                                 float* __restrict__ psum2) {
    constexpr int CP = F / 2;                 // col pairs
    constexpr int SL = 256 / CP;              // rows per block pass
    const int cp = threadIdx.x % CP;
    const int pr = blockIdx.x * SL + threadIdx.x / CP;
    const int PRT = gridDim.x * SL;
    float s0 = 0.f, s20 = 0.f, s1 = 0.f, s21 = 0.f;
    for (int r = pr; r < N; r += PRT) {
        ushort2 q = *reinterpret_cast<const ushort2*>(&in[(size_t)r * ldin + cp * 2]);
        const float a = bf2f(q.x), b = bf2f(q.y);
        s0 += a; s20 += a * a; s1 += b; s21 += b * b;
    }
    psum[(size_t)pr * F + cp * 2] = s0;
    psum[(size_t)pr * F + cp * 2 + 1] = s1;
    psum2[(size_t)pr * F + cp * 2] = s20;
    psum2[(size_t)pr * F + cp * 2 + 1] = s21;
}

template<int F>
__global__ __launch_bounds__(256) void k_bn_fin(const float* __restrict__ psum,
                                                const float* __restrict__ psum2, int PRT,
                                                const float* __restrict__ gamma,
                                                const float* __restrict__ beta,
                                                float* __restrict__ scale,
                                                float* __restrict__ shift, int N) {
    const int col = blockIdx.x;
    float s = 0.f, s2 = 0.f;
    for (int p = threadIdx.x; p < PRT; p += 256) {
        s += psum[(size_t)p * F + col];
        s2 += psum2[(size_t)p * F + col];
    }
#pragma unroll
    for (int off = 32; off; off >>= 1) {
        s += __shfl_down(s, off);
        s2 += __shfl_down(s2, off);
    }
    __shared__ float sm[4], sm2[4];
    const int wave = threadIdx.x >> 6, lane = threadIdx.x & 63;
    if (lane == 0) { sm[wave] = s; sm2[wave] = s2; }
    __syncthreads();
    if (threadIdx.x == 0) {
        s = sm[0] + sm[1] + sm[2] + sm[3];
        s2 = sm2[0] + sm2[1] + sm2[2] + sm2[3];
        float mu = s / N;
        float var = s2 / N - mu * mu;
        float isd = rsqrtf(var + 1e-5f);
        float g = gamma[col];
        scale[col] = g * isd;
        shift[col] = beta[col] - g * isd * mu;
    }
}

// ------------------------------- launcher ---------------------------------
extern "C" void kernel_launch(void* const* d_in, const int* in_sizes, int n_in,
                              void* d_out, int out_size, void* d_ws, size_t ws_size,
                              hipStream_t stream) {
    const float* x           = (const float*)d_in[0];
    const int*   src         = (const int*)d_in[1];
    const int*   dst         = (const int*)d_in[2];
    const float* W0          = (const float*)d_in[3];
    const float* attn_l0     = (const float*)d_in[4];
    const float* attn_r0     = (const float*)d_in[5];
    const float* resW0       = (const float*)d_in[6];
    const float* mid_bn_g    = (const float*)d_in[7];
    const float* mid_bn_b    = (const float*)d_in[8];
    const float* mid_W       = (const float*)d_in[9];
    const float* mid_attn_l  = (const float*)d_in[10];
    const float* mid_attn_r  = (const float*)d_in[11];
    const float* mid_resW    = (const float*)d_in[12];
    const float* norm_gamma  = (const float*)d_in[13];
    const float* norm_beta   = (const float*)d_in[14];
    const float* W_last      = (const float*)d_in[15];
    const float* attn_l_last = (const float*)d_in[16];
    const float* attn_r_last = (const float*)d_in[17];
    const float* resW_last   = (const float*)d_in[18];
    const float* bias_last   = (const float*)d_in[19];

    const int N = in_sizes[0] / IN_F;
    const int E = in_sizes[1];

    // ---- workspace carve-up (256B aligned) ----
    char* p = (char*)d_ws;
    size_t used = 0;
    auto take = [&](size_t bytes) -> char* {
        char* r = p;
        size_t adv = (bytes + 255) & ~(size_t)255;
        p += adv; used += adv;
        return r;
    };
    __hip_bfloat16* h       = (__hip_bfloat16*)take((size_t)N * HIDW * 2);
    __hip_bfloat16* ftb     = (__hip_bfloat16*)take((size_t)N * HIDW * 2);
    float*          el      = (float*)take((size_t)N * 4 * 4);
    float*          er      = (float*)take((size_t)N * 4 * 4);
    float*          oi      = (float*)take((size_t)N * 4);
    float*          insq    = (float*)take((size_t)N * 4);
    int*            indeg   = (int*)take((size_t)N * 4);
    int*            outdeg  = (int*)take((size_t)N * 4);
    int*            row_ptr = (int*)take((size_t)(N + 1) * 4);
    int*            cursor  = (int*)take((size_t)N * 4);
    int*            csr_src = (int*)take((size_t)E * 4);
    int*            bsum    = (int*)take(256 * 4);
    float*          psum    = (float*)take(1 << 20);
    float*          psum2   = (float*)take(1 << 20);
    float*          scale   = (float*)take(1024);
    float*          shift   = (float*)take(1024);
    __hip_bfloat16* Waug0     = (__hip_bfloat16*)take((size_t)272 * 256 * 2);
    __hip_bfloat16* midWaug   = (__hip_bfloat16*)take((size_t)4 * 144 * 128 * 2);
    __hip_bfloat16* resW0bf   = (__hip_bfloat16*)take(65536 * 2);
    __hip_bfloat16* midresWbf = (__hip_bfloat16*)take(65536 * 2);
    __hip_bfloat16* Wlastbf   = (__hip_bfloat16*)take(10240 * 2);
    __hip_bfloat16* resWlastbf= (__hip_bfloat16*)take(10240 * 2);
    if (used > ws_size) return;   // out of workspace: leave output poisoned (visible failure)

    const int nbN = (N + 255) / 256;
    const int NB4 = (N + 3) / 4;
    const int GWB = (N + 63) / 64;              // 64 rows/block (8 waves, col split)
    const int GWS = (N + 63) / 64;              // small kernel: 64 rows/block
    const int BNB = 512;                        // BN partial blocks

    // ---- graph prep ----
    hipMemsetAsync(indeg, 0, (size_t)N * 4, stream);
    hipMemsetAsync(outdeg, 0, (size_t)N * 4, stream);
    k_hist<<<1024, 256, 0, stream>>>(src, dst, E, outdeg, indeg);
    k_scan1<<<nbN, 256, 0, stream>>>(indeg, N, row_ptr + 1, bsum);
    k_scan2<<<1, 256, 0, stream>>>(bsum, nbN);
    k_scan3<<<nbN, 256, 0, stream>>>(row_ptr + 1, bsum, N);
    hipMemcpyAsync(cursor, row_ptr, (size_t)N * 4, hipMemcpyDeviceToDevice, stream);
    k_scatter<<<1024, 256, 0, stream>>>(src, dst, E, cursor, csr_src);
    k_deg<<<nbN, 256, 0, stream>>>(outdeg, indeg, oi, insq, N);

    // ---- weight conversion + augmentation ----
    k_cvt6<<<dim3(64, 4), 256, 0, stream>>>(resW0, resW0bf, 65536,
                                            mid_resW, midresWbf, 65536,
                                            W_last, Wlastbf, 10240,
                                            resW_last, resWlastbf, 10240,
                                            nullptr, nullptr, 0,
                                            nullptr, nullptr, 0);
    k_prepw<<<dim3(96, 5), 256, 0, stream>>>(W0, attn_l0, attn_r0,
                                             mid_W, mid_attn_l, mid_attn_r,
                                             Waug0, midWaug);

    // ---- layer 0: GATConv(256 -> 4x64), A = x (f32, no BN) ----
    k_gatconv_lds<256, 256, 256, 4, false, false, false><<<GWB, 512, 0, stream>>>(
        x, 256, Waug0, resW0bf, ftb, 256, h, 256, 0, N,
        nullptr, nullptr, oi, el, er);
    k_agg<4, 64, true><<<NB4, 256, 0, stream>>>(ftb, el, er, row_ptr, csr_src, oi, insq,
                                                h, 256, N);

    // ---- reversible middle layers ----
    for (int l = 0; l < 2; ++l) {
        for (int g = 0; g < 2; ++g) {
            const int inoff  = (g == 0) ? 128 : 0;
            const int outoff = (g == 0) ? 0 : 128;
            const int pg = l * 2 + g;
            k_bn_part<128><<<BNB, 256, 0, stream>>>(h + inoff, 256, N, psum, psum2);
            k_bn_fin<128><<<128, 256, 0, stream>>>(psum, psum2, BNB * 4,
                                                   mid_bn_g + pg * 128, mid_bn_b + pg * 128,
                                                   scale, shift, N);
            k_gatconv_lds<128, 128, 128, 4, true, true, true><<<GWB, 512, 0, stream>>>(
                h + inoff, 256, midWaug + (size_t)pg * 144 * 128, midresWbf + pg * 16384,
                ftb, 128, h, 256, outoff, N,
                scale, shift, oi, el, er);
            k_agg<4, 32, true><<<NB4, 256, 0, stream>>>(ftb, el, er, row_ptr, csr_src,
                                                        oi, insq, h + outoff, 256, N);
        }
    }

    // ---- final norm + GATConv(256 -> 1x40) + bias ----
    k_bn_part<256><<<BNB, 256, 0, stream>>>(h, 256, N, psum, psum2);
    k_bn_fin<256><<<256, 256, 0, stream>>>(psum, psum2, BNB * 2, norm_gamma, norm_beta,
                                           scale, shift, N);
    k_gatconv_sm<256, 40, 40, 1><<<GWS, 256, 0, stream>>>(
        h, 256, Wlastbf, resWlastbf, ftb, 40, (float*)d_out, 40, N,
        scale, shift, bias_last,
        attn_l_last, attn_r_last, oi, el, er);
    k_agg<1, 40, false><<<NB4, 256, 0, stream>>>(ftb, el, er, row_ptr, csr_src, oi, insq,
                                                 (float*)d_out, 40, N);
}

// Round 15
// 555.981 us; speedup vs baseline: 1.0675x; 1.0043x over previous
//
#include <hip/hip_runtime.h>
#include <hip/hip_bf16.h>

// ---------------------------------------------------------------------------
// RevGAT forward on MI355X.
// R2-R4: BN widened, k_agg single-pass, big fusion (706us).
// R5/R6/R10: col-split replication / no-LDS / 4-wave REGRESSED.
// R7-R9: LDS 8-wave col-split, swapped MFMA, el/er aug cols (581us).
// R11/R12: BM=32 queue + bf16 h (559us). R13: BN-fused agg REGRESSED.
// R14: R9 GEMM geometry + bf16 h I/O (558us). GEMM pinned ~60us with all
//      pipes <8% and occupancy 14% -> per-block stage latency exposed.
// R15: T14 async-STAGE pipeline: grid=ntiles/2, each block does 2 tiles;
//      next tile's global loads issued into regs BEFORE compute(t) ->
//      staging latency hidden under MFMA phase (exposed once per block).
// ---------------------------------------------------------------------------

#define IN_F   256
#define HIDW   256          // HEADS*HID
#define CLS    40

typedef __attribute__((ext_vector_type(8))) __bf16 bf16x8;
typedef __attribute__((ext_vector_type(4))) float  f32x4;

__device__ inline bf16x8 zb8() {
    bf16x8 v;
#pragma unroll
    for (int i = 0; i < 8; ++i) v[i] = (__bf16)0.f;
    return v;
}
__device__ inline bf16x8 ldb8(const __hip_bfloat16* p) {
    return *reinterpret_cast<const bf16x8*>(p);
}
__device__ inline float bf2f(unsigned short u) {
    union { unsigned int i; float f; } c;
    c.i = ((unsigned int)u) << 16;
    return c.f;
}
__device__ inline unsigned short f2bu(float f) {
    __hip_bfloat16 t = __float2bfloat16(f);
    union { __hip_bfloat16 b; unsigned short u; } c;
    c.b = t;
    return c.u;
}

// ------------------------------ graph prep --------------------------------
__global__ void k_hist(const int* __restrict__ src, const int* __restrict__ dst,
                       int E, int* __restrict__ outdeg, int* __restrict__ indeg) {
    for (int e = blockIdx.x * blockDim.x + threadIdx.x; e < E; e += gridDim.x * blockDim.x) {
        atomicAdd(&outdeg[src[e]], 1);
        atomicAdd(&indeg[dst[e]], 1);
    }
}

__global__ void k_scan1(const int* __restrict__ cnt, int N, int* __restrict__ rp1,
                        int* __restrict__ bsum) {
    __shared__ int sm[256];
    int i = blockIdx.x * 256 + threadIdx.x;
    int v = (i < N) ? cnt[i] : 0;
    sm[threadIdx.x] = v;
    __syncthreads();
    for (int off = 1; off < 256; off <<= 1) {
        int t = (threadIdx.x >= off) ? sm[threadIdx.x - off] : 0;
        __syncthreads();
        sm[threadIdx.x] += t;
        __syncthreads();
    }
    if (i < N) rp1[i] = sm[threadIdx.x];                  // inclusive within block
    if (threadIdx.x == 255) bsum[blockIdx.x] = sm[255];
}

__global__ void k_scan2(int* __restrict__ bsum, int nb) {
    __shared__ int sm[256];
    int v = (threadIdx.x < nb) ? bsum[threadIdx.x] : 0;
    sm[threadIdx.x] = v;
    __syncthreads();
    for (int off = 1; off < 256; off <<= 1) {
        int t = (threadIdx.x >= off) ? sm[threadIdx.x - off] : 0;
        __syncthreads();
        sm[threadIdx.x] += t;
        __syncthreads();
    }
    if (threadIdx.x < nb) bsum[threadIdx.x] = sm[threadIdx.x] - v;   // exclusive
}

__global__ void k_scan3(int* __restrict__ rp1, const int* __restrict__ bsumExcl, int N) {
    int i = blockIdx.x * 256 + threadIdx.x;
    if (i < N) rp1[i] += bsumExcl[blockIdx.x];
    if (blockIdx.x == 0 && threadIdx.x == 0) rp1[-1] = 0;            // row_ptr[0] = 0
}

__global__ void k_scatter(const int* __restrict__ src, const int* __restrict__ dst,
                          int E, int* __restrict__ cursor, int* __restrict__ csr_src) {
    for (int e = blockIdx.x * blockDim.x + threadIdx.x; e < E; e += gridDim.x * blockDim.x) {
        int d = dst[e];
        int pos = atomicAdd(&cursor[d], 1);
        csr_src[pos] = src[e];
    }
}

__global__ void k_deg(const int* __restrict__ outdeg, const int* __restrict__ indeg,
                      float* __restrict__ oi, float* __restrict__ insq, int N) {
    int i = blockIdx.x * 256 + threadIdx.x;
    if (i < N) {
        int od = outdeg[i]; if (od < 1) od = 1;
        int id = indeg[i];  if (id < 1) id = 1;
        oi[i]   = rsqrtf((float)od);
        insq[i] = sqrtf((float)id);
    }
}

// --------------------------- weight conversion ----------------------------
__global__ void k_cvt6(const float* s0, __hip_bfloat16* d0, int n0,
                       const float* s1, __hip_bfloat16* d1, int n1,
                       const float* s2, __hip_bfloat16* d2, int n2,
                       const float* s3, __hip_bfloat16* d3, int n3,
                       const float* s4, __hip_bfloat16* d4, int n4,
                       const float* s5, __hip_bfloat16* d5, int n5) {
    const float* ss; __hip_bfloat16* dd; int nn;
    switch (blockIdx.y) {
        case 0: ss = s0; dd = d0; nn = n0; break;
        case 1: ss = s1; dd = d1; nn = n1; break;
        case 2: ss = s2; dd = d2; nn = n2; break;
        case 3: ss = s3; dd = d3; nn = n3; break;
        case 4: ss = s4; dd = d4; nn = n4; break;
        default: ss = s5; dd = d5; nn = n5; break;
    }
    for (int i = blockIdx.x * blockDim.x + threadIdx.x; i < nn; i += gridDim.x * blockDim.x)
        dd[i] = __float2bfloat16(ss[i]);
}

// ----- augmented ft weights: rows 0..NF-1 = W, NF+j (j<4)=wl_h, (j<8)=wr_h,
//       NF+8..NF+15 = 0.  wl_h[k] = sum_d W[h*D+d, k]*attn_l[h*D+d] (f32). ---
__global__ void k_prepw(const float* __restrict__ W0,
                        const float* __restrict__ al0, const float* __restrict__ ar0,
                        const float* __restrict__ midW,
                        const float* __restrict__ midal, const float* __restrict__ midar,
                        __hip_bfloat16* __restrict__ Waug0,
                        __hip_bfloat16* __restrict__ midWaug) {
    const int layer = blockIdx.y;
    int NF, K, D;
    const float *W, *al, *ar;
    __hip_bfloat16* dst;
    if (layer == 0) {
        NF = 256; K = 256; D = 64;
        W = W0; al = al0; ar = ar0; dst = Waug0;
    } else {
        const int pg = layer - 1;
        NF = 128; K = 128; D = 32;
        W = midW + pg * 16384; al = midal + pg * 128; ar = midar + pg * 128;
        dst = midWaug + (size_t)pg * 144 * 128;
    }
    const int total = (NF + 16) * K;
    for (int idx = blockIdx.x * 256 + threadIdx.x; idx < total; idx += gridDim.x * 256) {
        const int col = idx / K, k = idx % K;
        float v = 0.f;
        if (col < NF) {
            v = W[(size_t)col * K + k];
        } else {
            const int j = col - NF;
            if (j < 8) {
                const int head = j & 3;
                const float* at = (j < 4) ? al : ar;
                float s = 0.f;
                for (int d = 0; d < D; ++d)
                    s += W[(size_t)(head * D + d) * K + k] * at[head * D + d];
                v = s;
            }
        }
        dst[idx] = __float2bfloat16(v);
    }
}

// ----------------- pipelined LDS-staged GATConv GEMM (K=128/256) ----------
// 512 thr (8 waves), BM=64, 2 tiles/block (grid = ceil(ntiles/2)).
// T14 async-STAGE: next tile's global loads issued into regs before
// compute(t); write_lds after the post-compute barrier. Waves col-split
// (ft 0-3 / res 4-7); swapped mfma -> ushort4 stores; wave0 aug el/er tile.
template<int K, int NF, int NR, int H, bool BN, bool ABF, bool ADDRES>
__global__ __launch_bounds__(512) void k_gatconv_lds(
    const void* __restrict__ Ain, int lda,
    const __hip_bfloat16* __restrict__ Waug,
    const __hip_bfloat16* __restrict__ Wres,
    __hip_bfloat16* __restrict__ ftb, int ldft,
    __hip_bfloat16* __restrict__ hout, int ldh, int houtoff,
    int M, int ntiles,
    const float* __restrict__ scale, const float* __restrict__ shift,
    const float* __restrict__ oi,
    float* __restrict__ el, float* __restrict__ er) {
    constexpr int BM = 64, KF = K / 32, NTOT = NF + NR;
    constexpr int CW = NTOT / 8, CT = CW / 16;
    constexpr int NRT = BM / 16;
    constexpr int CPR = K / 8;            // 8-elem chunks per row
    constexpr int RSTEP = 512 / CPR;      // rows per staging pass
    constexpr int PASS = BM / RSTEP;      // passes per tile (4 @K=256, 2 @K=128)
    static_assert(NTOT % 8 == 0 && CW % 16 == 0, "col split");
    static_assert(NF % CW == 0, "ft/res wave boundary");
    static_assert(H == 4, "el/er float4 stores assume H==4");
    __shared__ bf16x8 ldsA[NRT * KF * 64];
    const int tid = threadIdx.x;
    const int wv = tid >> 6, lane = tid & 63, rf = lane & 15, kg = lane >> 4;

    // staging thread geometry
    const int c16 = tid % CPR;
    const int ec = c16 * 8;
    const int skf = c16 >> 2, skg = c16 & 3;
    const int srow = tid / CPR;

    float bnsc[8], bnsh[8];
    if (BN) {
        float4 s01 = *reinterpret_cast<const float4*>(scale + ec);
        float4 s23 = *reinterpret_cast<const float4*>(scale + ec + 4);
        float4 h01 = *reinterpret_cast<const float4*>(shift + ec);
        float4 h23 = *reinterpret_cast<const float4*>(shift + ec + 4);
        bnsc[0]=s01.x; bnsc[1]=s01.y; bnsc[2]=s01.z; bnsc[3]=s01.w;
        bnsc[4]=s23.x; bnsc[5]=s23.y; bnsc[6]=s23.z; bnsc[7]=s23.w;
        bnsh[0]=h01.x; bnsh[1]=h01.y; bnsh[2]=h01.z; bnsh[3]=h01.w;
        bnsh[4]=h23.x; bnsh[5]=h23.y; bnsh[6]=h23.z; bnsh[7]=h23.w;
    }

    // staging registers (statically indexed)
    float4 rA[PASS][2];
    bf16x8 rAb[PASS];

    const bool isft = (wv * CW) < NF;
    const int colbase = isft ? wv * CW : wv * CW - NF;
    const __hip_bfloat16* __restrict__ Wb = isft ? Waug : Wres;

    auto load_regs = [&](int t) {
#pragma unroll
        for (int pz = 0; pz < PASS; ++pz) {
            const int gr = t * BM + pz * RSTEP + srow;
            if (ABF) {
                rAb[pz] = (gr < M)
                    ? ldb8((const __hip_bfloat16*)Ain + (size_t)gr * lda + ec)
                    : zb8();
            } else {
                if (gr < M) {
                    const float* ap = (const float*)Ain + (size_t)gr * lda + ec;
                    rA[pz][0] = *reinterpret_cast<const float4*>(ap);
                    rA[pz][1] = *reinterpret_cast<const float4*>(ap + 4);
                } else {
                    rA[pz][0] = {0.f, 0.f, 0.f, 0.f};
                    rA[pz][1] = {0.f, 0.f, 0.f, 0.f};
                }
            }
        }
    };
    auto write_lds = [&]() {
#pragma unroll
        for (int pz = 0; pz < PASS; ++pz) {
            const int r = pz * RSTEP + srow;
            bf16x8 tv;
            if (ABF) {
                if (BN) {
#pragma unroll
                    for (int i = 0; i < 8; ++i)
                        tv[i] = (__bf16)fmaxf((float)rAb[pz][i] * bnsc[i] + bnsh[i], 0.f);
                } else {
                    tv = rAb[pz];
                }
            } else {
                float v[8] = {rA[pz][0].x, rA[pz][0].y, rA[pz][0].z, rA[pz][0].w,
                              rA[pz][1].x, rA[pz][1].y, rA[pz][1].z, rA[pz][1].w};
#pragma unroll
                for (int i = 0; i < 8; ++i) {
                    float u = v[i];
                    if (BN) u = fmaxf(u * bnsc[i] + bnsh[i], 0.f);
                    tv[i] = (__bf16)u;
                }
            }
            ldsA[((r >> 4) * KF + skf) * 64 + ((skg * 16 + (r & 15)) ^ skf)] = tv;
        }
    };

    int t = blockIdx.x;
    load_regs(t);
    while (t < ntiles) {
        write_lds();
        __syncthreads();
        const int tn = t + gridDim.x;
        if (tn < ntiles) load_regs(tn);     // in flight during compute below

        const int row0 = t * BM;
        for (int ct = 0; ct < CT; ++ct) {
            const int tcol = colbase + ct * 16;
            bf16x8 w[KF];
            const __hip_bfloat16* bp = Wb + (size_t)(tcol + rf) * K + kg * 8;
#pragma unroll
            for (int kf = 0; kf < KF; ++kf) w[kf] = ldb8(bp + kf * 32);
#pragma unroll
            for (int rtp = 0; rtp < NRT / 2; ++rtp) {
                f32x4 acc0 = {0.f, 0.f, 0.f, 0.f};
                f32x4 acc1 = {0.f, 0.f, 0.f, 0.f};
#pragma unroll
                for (int kf = 0; kf < KF; ++kf) {
                    const bf16x8 a0 = ldsA[((2 * rtp) * KF + kf) * 64 + (lane ^ kf)];
                    const bf16x8 a1 = ldsA[((2 * rtp + 1) * KF + kf) * 64 + (lane ^ kf)];
                    acc0 = __builtin_amdgcn_mfma_f32_16x16x32_bf16(w[kf], a0, acc0, 0, 0, 0);
                    acc1 = __builtin_amdgcn_mfma_f32_16x16x32_bf16(w[kf], a1, acc1, 0, 0, 0);
                }
                const int r0g = row0 + 2 * rtp * 16 + rf;
                const int r1g = r0g + 16;
                const int c4 = tcol + 4 * kg;
                ushort4 q0 = {f2bu(acc0[0]), f2bu(acc0[1]), f2bu(acc0[2]), f2bu(acc0[3])};
                ushort4 q1 = {f2bu(acc1[0]), f2bu(acc1[1]), f2bu(acc1[2]), f2bu(acc1[3])};
                if (isft) {
                    if (r0g < M)
                        *reinterpret_cast<ushort4*>(&ftb[(size_t)r0g * ldft + c4]) = q0;
                    if (r1g < M)
                        *reinterpret_cast<ushort4*>(&ftb[(size_t)r1g * ldft + c4]) = q1;
                } else {
                    if (r0g < M) {
                        __hip_bfloat16* hp = hout + (size_t)r0g * ldh + houtoff + c4;
                        if (ADDRES) {
                            ushort4 cur = *reinterpret_cast<ushort4*>(hp);
                            q0.x = f2bu(bf2f(cur.x) + acc0[0]);
                            q0.y = f2bu(bf2f(cur.y) + acc0[1]);
                            q0.z = f2bu(bf2f(cur.z) + acc0[2]);
                            q0.w = f2bu(bf2f(cur.w) + acc0[3]);
                        }
                        *reinterpret_cast<ushort4*>(hp) = q0;
                    }
                    if (r1g < M) {
                        __hip_bfloat16* hp = hout + (size_t)r1g * ldh + houtoff + c4;
                        if (ADDRES) {
                            ushort4 cur = *reinterpret_cast<ushort4*>(hp);
                            q1.x = f2bu(bf2f(cur.x) + acc1[0]);
                            q1.y = f2bu(bf2f(cur.y) + acc1[1]);
                            q1.z = f2bu(bf2f(cur.z) + acc1[2]);
                            q1.w = f2bu(bf2f(cur.w) + acc1[3]);
                        }
                        *reinterpret_cast<ushort4*>(hp) = q1;
                    }
                }
            }
        }

        // ---- aug tile (el/er), wave 0 only ----
        if (wv == 0) {
            bf16x8 w[KF];
            const __hip_bfloat16* bp = Waug + (size_t)(NF + rf) * K + kg * 8;
#pragma unroll
            for (int kf = 0; kf < KF; ++kf) w[kf] = ldb8(bp + kf * 32);
#pragma unroll
            for (int rtp = 0; rtp < NRT / 2; ++rtp) {
                f32x4 acc0 = {0.f, 0.f, 0.f, 0.f};
                f32x4 acc1 = {0.f, 0.f, 0.f, 0.f};
#pragma unroll
                for (int kf = 0; kf < KF; ++kf) {
                    const bf16x8 a0 = ldsA[((2 * rtp) * KF + kf) * 64 + (lane ^ kf)];
                    const bf16x8 a1 = ldsA[((2 * rtp + 1) * KF + kf) * 64 + (lane ^ kf)];
                    acc0 = __builtin_amdgcn_mfma_f32_16x16x32_bf16(w[kf], a0, acc0, 0, 0, 0);
                    acc1 = __builtin_amdgcn_mfma_f32_16x16x32_bf16(w[kf], a1, acc1, 0, 0, 0);
                }
                const int r0g = row0 + 2 * rtp * 16 + rf;
                const int r1g = r0g + 16;
                if (kg == 0) {
                    if (r0g < M) {
                        const float o = oi[r0g];
                        float4 v = {acc0[0] * o, acc0[1] * o, acc0[2] * o, acc0[3] * o};
                        *reinterpret_cast<float4*>(&el[(size_t)r0g * 4]) = v;
                    }
                    if (r1g < M) {
                        const float o = oi[r1g];
                        float4 v = {acc1[0] * o, acc1[1] * o, acc1[2] * o, acc1[3] * o};
                        *reinterpret_cast<float4*>(&el[(size_t)r1g * 4]) = v;
                    }
                } else if (kg == 1) {
                    if (r0g < M) {
                        float4 v = {acc0[0], acc0[1], acc0[2], acc0[3]};
                        *reinterpret_cast<float4*>(&er[(size_t)r0g * 4]) = v;
                    }
                    if (r1g < M) {
                        float4 v = {acc1[0], acc1[1], acc1[2], acc1[3]};
                        *reinterpret_cast<float4*>(&er[(size_t)r1g * 4]) = v;
                    }
                }
            }
        }
        __syncthreads();        // LDS safe to overwrite next iteration
        t = tn;
    }
}

// -------- small merged GATConv (last layer, NOUT=40), bf16 A -------------
template<int K, int NF, int NR, int H>
__global__ __launch_bounds__(256) void k_gatconv_sm(
    const __hip_bfloat16* __restrict__ A, int lda,
    const __hip_bfloat16* __restrict__ Wft,
    const __hip_bfloat16* __restrict__ Wres,
    __hip_bfloat16* __restrict__ ftb, int ldft,
    float* __restrict__ Cres, int ldcres,
    int M,
    const float* __restrict__ scale, const float* __restrict__ shift,
    const float* __restrict__ bias,
    const float* __restrict__ attn_l, const float* __restrict__ attn_r,
    const float* __restrict__ oi,
    float* __restrict__ el, float* __restrict__ er) {
    constexpr int KF   = K / 32;
    constexpr int NCTF = (NF + 15) / 16;
    constexpr int NCTR = (NR + 15) / 16;
    constexpr int CTH  = NCTF / H;
    static_assert(NCTF % H == 0, "head tiling");
    const int wave = threadIdx.x >> 6, lane = threadIdx.x & 63;
    const int row0 = blockIdx.x * 64 + wave * 16;
    const int rf = lane & 15, kg = lane >> 4;

    bf16x8 a[KF];
    {
        const int row = row0 + rf;
        const bool rok = row < M;
#pragma unroll
        for (int kf = 0; kf < KF; ++kf) {
            const int c0 = kg * 8 + kf * 32;
            if (rok) {
                bf16x8 raw = ldb8(A + (size_t)row * lda + c0);
                float4 s01 = *reinterpret_cast<const float4*>(scale + c0);
                float4 s23 = *reinterpret_cast<const float4*>(scale + c0 + 4);
                float4 h01 = *reinterpret_cast<const float4*>(shift + c0);
                float4 h23 = *reinterpret_cast<const float4*>(shift + c0 + 4);
                float sc[8] = {s01.x,s01.y,s01.z,s01.w,s23.x,s23.y,s23.z,s23.w};
                float sh[8] = {h01.x,h01.y,h01.z,h01.w,h23.x,h23.y,h23.z,h23.w};
                bf16x8 t;
#pragma unroll
                for (int i = 0; i < 8; ++i)
                    t[i] = (__bf16)fmaxf((float)raw[i] * sc[i] + sh[i], 0.f);
                a[kf] = t;
            } else {
                a[kf] = zb8();
            }
        }
    }

    int ct = 0;
    for (int hh = 0; hh < H; ++hh) {
        float elp[4] = {0.f, 0.f, 0.f, 0.f};
        float erp[4] = {0.f, 0.f, 0.f, 0.f};
        for (int cth = 0; cth < CTH; ++cth, ++ct) {
            const int ccol = ct * 16 + rf;
            bf16x8 b[KF];
            const __hip_bfloat16* bp = Wft + (size_t)ccol * K + kg * 8;
#pragma unroll
            for (int kf = 0; kf < KF; ++kf)
                b[kf] = (ccol < NF) ? ldb8(bp + kf * 32) : zb8();
            f32x4 acc = {0.f, 0.f, 0.f, 0.f};
#pragma unroll
            for (int kf = 0; kf < KF; ++kf)
                acc = __builtin_amdgcn_mfma_f32_16x16x32_bf16(a[kf], b[kf], acc, 0, 0, 0);
            float al = 0.f, ar = 0.f;
            if (ccol < NF) { al = attn_l[ccol]; ar = attn_r[ccol]; }
            if (ccol < NF) {
#pragma unroll
                for (int r = 0; r < 4; ++r) {
                    const float v = acc[r];
                    elp[r] += v * al; erp[r] += v * ar;
                    const int row = row0 + kg * 4 + r;
                    if (row < M)
                        ftb[(size_t)row * ldft + ccol] = __float2bfloat16(v);
                }
            }
        }
#pragma unroll
        for (int off = 1; off <= 8; off <<= 1)
#pragma unroll
            for (int r = 0; r < 4; ++r) {
                elp[r] += __shfl_xor(elp[r], off);
                erp[r] += __shfl_xor(erp[r], off);
            }
        if (rf == 0) {
#pragma unroll
            for (int r = 0; r < 4; ++r) {
                const int row = row0 + kg * 4 + r;
                if (row < M) {
                    el[(size_t)row * H + hh] = oi[row] * elp[r];
                    er[(size_t)row * H + hh] = erp[r];
                }
            }
        }
    }

    for (int rt = 0; rt < NCTR; ++rt) {
        const int ccol = rt * 16 + rf;
        bf16x8 b[KF];
        const __hip_bfloat16* bp = Wres + (size_t)ccol * K + kg * 8;
#pragma unroll
        for (int kf = 0; kf < KF; ++kf)
            b[kf] = (ccol < NR) ? ldb8(bp + kf * 32) : zb8();
        f32x4 acc = {0.f, 0.f, 0.f, 0.f};
#pragma unroll
        for (int kf = 0; kf < KF; ++kf)
            acc = __builtin_amdgcn_mfma_f32_16x16x32_bf16(a[kf], b[kf], acc, 0, 0, 0);
        if (ccol < NR) {
#pragma unroll
            for (int r = 0; r < 4; ++r) {
                const int row = row0 + kg * 4 + r;
                if (row < M) {
                    float v = acc[r];
                    if (bias) v += bias[ccol];
                    Cres[(size_t)row * ldcres + ccol] = v;
                }
            }
        }
    }
}

// ------------- fused edge softmax + message aggregation (per dst) ---------
template<int EPL>
__device__ inline void ldrow(const __hip_bfloat16* fp, float* f) {
    if constexpr (EPL == 4) {
        ushort4 q = *reinterpret_cast<const ushort4*>(fp);
        f[0] = bf2f(q.x); f[1] = bf2f(q.y); f[2] = bf2f(q.z); f[3] = bf2f(q.w);
    } else if constexpr (EPL == 2) {
        ushort2 q = *reinterpret_cast<const ushort2*>(fp);
        f[0] = bf2f(q.x); f[1] = bf2f(q.y);
    } else {
        f[0] = bf2f(*reinterpret_cast<const unsigned short*>(fp));
    }
}
__device__ inline float escore(float sc) {
    sc = sc >= 0.f ? sc : 0.2f * sc;
    sc = fminf(fmaxf(sc, -30.f), 30.f);
    return __expf(sc);
}

// OBF: out is bf16 (RMW); else f32 (RMW).
template<int H, int D, bool OBF>
__global__ __launch_bounds__(256) void k_agg(
    const __hip_bfloat16* __restrict__ ftb,
    const float* __restrict__ el, const float* __restrict__ er,
    const int* __restrict__ row_ptr, const int* __restrict__ csr_src,
    const float* __restrict__ oi, const float* __restrict__ insq,
    void* __restrict__ out, int ldc, int N) {
    constexpr int W = H * D;
    constexpr int EPL = (W >= 64) ? (W / 64) : 1;
    const int lane = threadIdx.x & 63;
    const int v = blockIdx.x * 4 + (threadIdx.x >> 6);
    if (v >= N) return;
    if (W < 64 && lane >= W) return;
    const int col0 = lane * EPL;
    const int myh = (W >= 64) ? (col0 / D) : 0;
    const int s = row_ptr[v], e = row_ptr[v + 1];
    const float erv = er[(size_t)v * H + myh];

    float denom = 0.f;
    float acc[EPL];
#pragma unroll
    for (int k = 0; k < EPL; ++k) acc[k] = 0.f;

    int p = s;
    for (; p + 3 < e; p += 4) {
        const int u0 = csr_src[p + 0], u1 = csr_src[p + 1];
        const int u2 = csr_src[p + 2], u3 = csr_src[p + 3];
        float f0[EPL], f1[EPL], f2[EPL], f3[EPL];
        ldrow<EPL>(ftb + (size_t)u0 * W + col0, f0);
        ldrow<EPL>(ftb + (size_t)u1 * W + col0, f1);
        ldrow<EPL>(ftb + (size_t)u2 * W + col0, f2);
        ldrow<EPL>(ftb + (size_t)u3 * W + col0, f3);
        const float s0 = el[(size_t)u0 * H + myh], s1 = el[(size_t)u1 * H + myh];
        const float s2 = el[(size_t)u2 * H + myh], s3 = el[(size_t)u3 * H + myh];
        const float o0 = oi[u0], o1 = oi[u1], o2 = oi[u2], o3 = oi[u3];
        const float w0 = escore(s0 + erv), w1 = escore(s1 + erv);
        const float w2 = escore(s2 + erv), w3 = escore(s3 + erv);
        denom += (w0 + w1) + (w2 + w3);
        const float a0 = w0 * o0, a1 = w1 * o1, a2 = w2 * o2, a3 = w3 * o3;
#pragma unroll
        for (int k = 0; k < EPL; ++k)
            acc[k] += a0 * f0[k] + a1 * f1[k] + a2 * f2[k] + a3 * f3[k];
    }
    for (; p < e; ++p) {
        const int u = csr_src[p];
        float f[EPL];
        ldrow<EPL>(ftb + (size_t)u * W + col0, f);
        const float w = escore(el[(size_t)u * H + myh] + erv);
        denom += w;
        const float a = w * oi[u];
#pragma unroll
        for (int k = 0; k < EPL; ++k) acc[k] += a * f[k];
    }

    const float iv = insq[v] / fmaxf(denom, 1e-9f);
    if (OBF) {
        __hip_bfloat16* op = (__hip_bfloat16*)out + (size_t)v * ldc + col0;
        if constexpr (EPL == 4) {
            ushort4 o = *reinterpret_cast<ushort4*>(op);
            o.x = f2bu(bf2f(o.x) + iv * acc[0]);
            o.y = f2bu(bf2f(o.y) + iv * acc[1]);
            o.z = f2bu(bf2f(o.z) + iv * acc[2]);
            o.w = f2bu(bf2f(o.w) + iv * acc[3]);
            *reinterpret_cast<ushort4*>(op) = o;
        } else if constexpr (EPL == 2) {
            ushort2 o = *reinterpret_cast<ushort2*>(op);
            o.x = f2bu(bf2f(o.x) + iv * acc[0]);
            o.y = f2bu(bf2f(o.y) + iv * acc[1]);
            *reinterpret_cast<ushort2*>(op) = o;
        } else {
            unsigned short* up = (unsigned short*)op;
            *up = f2bu(bf2f(*up) + iv * acc[0]);
        }
    } else {
        float* op = (float*)out + (size_t)v * ldc + col0;
        if constexpr (EPL == 4) {
            float4 o = *reinterpret_cast<float4*>(op);
            o.x += iv * acc[0]; o.y += iv * acc[1]; o.z += iv * acc[2]; o.w += iv * acc[3];
            *reinterpret_cast<float4*>(op) = o;
        } else if constexpr (EPL == 2) {
            float2 o = *reinterpret_cast<float2*>(op);
            o.x += iv * acc[0]; o.y += iv * acc[1];
            *reinterpret_cast<float2*>(op) = o;
        } else {
            op[0] += iv * acc[0];
        }
    }
}

// ------------------------------ batch norm (bf16 input) -------------------
template<int F>
__global__ __launch_bounds__(256) void k_bn_part(const __hip_bfloat16* __restrict__ in,
                                                 int ldin, int N,
                                                 float* __restrict__ psum,
                                                 float* __restrict__ psum2) {
    constexpr int CP = F / 2;                 // col pairs
    constexpr int SL = 256 / CP;              // rows per block pass
    const int cp = threadIdx.x % CP;
    const int pr = blockIdx.x * SL + threadIdx.x / CP;
    const int PRT = gridDim.x * SL;
    float s0 = 0.f, s20 = 0.f, s1 = 0.f, s21 = 0.f;
    for (int r = pr; r < N; r += PRT) {
        ushort2 q = *reinterpret_cast<const ushort2*>(&in[(size_t)r * ldin + cp * 2]);
        const float a = bf2f(q.x), b = bf2f(q.y);
        s0 += a; s20 += a * a; s1 += b; s21 += b * b;
    }
    psum[(size_t)pr * F + cp * 2] = s0;
    psum[(size_t)pr * F + cp * 2 + 1] = s1;
    psum2[(size_t)pr * F + cp * 2] = s20;
    psum2[(size_t)pr * F + cp * 2 + 1] = s21;
}

template<int F>
__global__ __launch_bounds__(256) void k_bn_fin(const float* __restrict__ psum,
                                                const float* __restrict__ psum2, int PRT,
                                                const float* __restrict__ gamma,
                                                const float* __restrict__ beta,
                                                float* __restrict__ scale,
                                                float* __restrict__ shift, int N) {
    const int col = blockIdx.x;
    float s = 0.f, s2 = 0.f;
    for (int p = threadIdx.x; p < PRT; p += 256) {
        s += psum[(size_t)p * F + col];
        s2 += psum2[(size_t)p * F + col];
    }
#pragma unroll
    for (int off = 32; off; off >>= 1) {
        s += __shfl_down(s, off);
        s2 += __shfl_down(s2, off);
    }
    __shared__ float sm[4], sm2[4];
    const int wave = threadIdx.x >> 6, lane = threadIdx.x & 63;
    if (lane == 0) { sm[wave] = s; sm2[wave] = s2; }
    __syncthreads();
    if (threadIdx.x == 0) {
        s = sm[0] + sm[1] + sm[2] + sm[3];
        s2 = sm2[0] + sm2[1] + sm2[2] + sm2[3];
        float mu = s / N;
        float var = s2 / N - mu * mu;
        float isd = rsqrtf(var + 1e-5f);
        float g = gamma[col];
        scale[col] = g * isd;
        shift[col] = beta[col] - g * isd * mu;
    }
}

// ------------------------------- launcher ---------------------------------
extern "C" void kernel_launch(void* const* d_in, const int* in_sizes, int n_in,
                              void* d_out, int out_size, void* d_ws, size_t ws_size,
                              hipStream_t stream) {
    const float* x           = (const float*)d_in[0];
    const int*   src         = (const int*)d_in[1];
    const int*   dst         = (const int*)d_in[2];
    const float* W0          = (const float*)d_in[3];
    const float* attn_l0     = (const float*)d_in[4];
    const float* attn_r0     = (const float*)d_in[5];
    const float* resW0       = (const float*)d_in[6];
    const float* mid_bn_g    = (const float*)d_in[7];
    const float* mid_bn_b    = (const float*)d_in[8];
    const float* mid_W       = (const float*)d_in[9];
    const float* mid_attn_l  = (const float*)d_in[10];
    const float* mid_attn_r  = (const float*)d_in[11];
    const float* mid_resW    = (const float*)d_in[12];
    const float* norm_gamma  = (const float*)d_in[13];
    const float* norm_beta   = (const float*)d_in[14];
    const float* W_last      = (const float*)d_in[15];
    const float* attn_l_last = (const float*)d_in[16];
    const float* attn_r_last = (const float*)d_in[17];
    const float* resW_last   = (const float*)d_in[18];
    const float* bias_last   = (const float*)d_in[19];

    const int N = in_sizes[0] / IN_F;
    const int E = in_sizes[1];

    // ---- workspace carve-up (256B aligned) ----
    char* p = (char*)d_ws;
    size_t used = 0;
    auto take = [&](size_t bytes) -> char* {
        char* r = p;
        size_t adv = (bytes + 255) & ~(size_t)255;
        p += adv; used += adv;
        return r;
    };
    __hip_bfloat16* h       = (__hip_bfloat16*)take((size_t)N * HIDW * 2);
    __hip_bfloat16* ftb     = (__hip_bfloat16*)take((size_t)N * HIDW * 2);
    float*          el      = (float*)take((size_t)N * 4 * 4);
    float*          er      = (float*)take((size_t)N * 4 * 4);
    float*          oi      = (float*)take((size_t)N * 4);
    float*          insq    = (float*)take((size_t)N * 4);
    int*            indeg   = (int*)take((size_t)N * 4);
    int*            outdeg  = (int*)take((size_t)N * 4);
    int*            row_ptr = (int*)take((size_t)(N + 1) * 4);
    int*            cursor  = (int*)take((size_t)N * 4);
    int*            csr_src = (int*)take((size_t)E * 4);
    int*            bsum    = (int*)take(256 * 4);
    float*          psum    = (float*)take(1 << 20);
    float*          psum2   = (float*)take(1 << 20);
    float*          scale   = (float*)take(1024);
    float*          shift   = (float*)take(1024);
    __hip_bfloat16* Waug0     = (__hip_bfloat16*)take((size_t)272 * 256 * 2);
    __hip_bfloat16* midWaug   = (__hip_bfloat16*)take((size_t)4 * 144 * 128 * 2);
    __hip_bfloat16* resW0bf   = (__hip_bfloat16*)take(65536 * 2);
    __hip_bfloat16* midresWbf = (__hip_bfloat16*)take(65536 * 2);
    __hip_bfloat16* Wlastbf   = (__hip_bfloat16*)take(10240 * 2);
    __hip_bfloat16* resWlastbf= (__hip_bfloat16*)take(10240 * 2);
    if (used > ws_size) return;   // out of workspace: leave output poisoned (visible failure)

    const int nbN = (N + 255) / 256;
    const int NB4 = (N + 3) / 4;
    const int NT  = (N + 63) / 64;              // GEMM row-tiles (BM=64)
    const int GWP = (NT + 1) / 2;               // pipelined: 2 tiles/block
    const int GWS = (N + 63) / 64;              // small kernel: 64 rows/block
    const int BNB = 512;                        // BN partial blocks

    // ---- graph prep ----
    hipMemsetAsync(indeg, 0, (size_t)N * 4, stream);
    hipMemsetAsync(outdeg, 0, (size_t)N * 4, stream);
    k_hist<<<1024, 256, 0, stream>>>(src, dst, E, outdeg, indeg);
    k_scan1<<<nbN, 256, 0, stream>>>(indeg, N, row_ptr + 1, bsum);
    k_scan2<<<1, 256, 0, stream>>>(bsum, nbN);
    k_scan3<<<nbN, 256, 0, stream>>>(row_ptr + 1, bsum, N);
    hipMemcpyAsync(cursor, row_ptr, (size_t)N * 4, hipMemcpyDeviceToDevice, stream);
    k_scatter<<<1024, 256, 0, stream>>>(src, dst, E, cursor, csr_src);
    k_deg<<<nbN, 256, 0, stream>>>(outdeg, indeg, oi, insq, N);

    // ---- weight conversion + augmentation ----
    k_cvt6<<<dim3(64, 4), 256, 0, stream>>>(resW0, resW0bf, 65536,
                                            mid_resW, midresWbf, 65536,
                                            W_last, Wlastbf, 10240,
                                            resW_last, resWlastbf, 10240,
                                            nullptr, nullptr, 0,
                                            nullptr, nullptr, 0);
    k_prepw<<<dim3(96, 5), 256, 0, stream>>>(W0, attn_l0, attn_r0,
                                             mid_W, mid_attn_l, mid_attn_r,
                                             Waug0, midWaug);

    // ---- layer 0: GATConv(256 -> 4x64), A = x (f32, no BN) ----
    k_gatconv_lds<256, 256, 256, 4, false, false, false><<<GWP, 512, 0, stream>>>(
        x, 256, Waug0, resW0bf, ftb, 256, h, 256, 0, N, NT,
        nullptr, nullptr, oi, el, er);
    k_agg<4, 64, true><<<NB4, 256, 0, stream>>>(ftb, el, er, row_ptr, csr_src, oi, insq,
                                                h, 256, N);

    // ---- reversible middle layers ----
    for (int l = 0; l < 2; ++l) {
        for (int g = 0; g < 2; ++g) {
            const int inoff  = (g == 0) ? 128 : 0;
            const int outoff = (g == 0) ? 0 : 128;
            const int pg = l * 2 + g;
            k_bn_part<128><<<BNB, 256, 0, stream>>>(h + inoff, 256, N, psum, psum2);
            k_bn_fin<128><<<128, 256, 0, stream>>>(psum, psum2, BNB * 4,
                                                   mid_bn_g + pg * 128, mid_bn_b + pg * 128,
                                                   scale, shift, N);
            k_gatconv_lds<128, 128, 128, 4, true, true, true><<<GWP, 512, 0, stream>>>(
                h + inoff, 256, midWaug + (size_t)pg * 144 * 128, midresWbf + pg * 16384,
                ftb, 128, h, 256, outoff, N, NT,
                scale, shift, oi, el, er);
            k_agg<4, 32, true><<<NB4, 256, 0, stream>>>(ftb, el, er, row_ptr, csr_src,
                                                        oi, insq, h + outoff, 256, N);
        }
    }

    // ---- final norm + GATConv(256 -> 1x40) + bias ----
    k_bn_part<256><<<BNB, 256, 0, stream>>>(h, 256, N, psum, psum2);
    k_bn_fin<256><<<256, 256, 0, stream>>>(psum, psum2, BNB * 2, norm_gamma, norm_beta,
                                           scale, shift, N);
    k_gatconv_sm<256, 40, 40, 1><<<GWS, 256, 0, stream>>>(
        h, 256, Wlastbf, resWlastbf, ftb, 40, (float*)d_out, 40, N,
        scale, shift, bias_last,
        attn_l_last, attn_r_last, oi, el, er);
    k_agg<1, 40, false><<<NB4, 256, 0, stream>>>(ftb, el, er, row_ptr, csr_src, oi, insq,
                                                 (float*)d_out, 40, N);
}

// Round 16
// 535.184 us; speedup vs baseline: 1.1090x; 1.0389x over previous
//
#include <hip/hip_runtime.h>
#include <hip/hip_bf16.h>

// ---------------------------------------------------------------------------
// RevGAT forward on MI355X.
// R2-R4: BN widened, k_agg single-pass, big fusion (706us).
// R5/R6/R10: col-split replication / no-LDS / 4-wave REGRESSED.
// R7-R9: LDS 8-wave col-split, swapped MFMA, el/er aug cols (581us).
// R11/R12: BM=32 queue + bf16 h (559us). R13: BN-fused agg REGRESSED.
// R14/R15: R9 geometry + bf16 h + T14 pipeline (556us). GEMM pinned ~60us
//      across 9 structural variants, all pipes <8% -> declared closed.
// R16: k_agg lanes-per-node split: W=128 uses 32-lane half-waves (8B/lane
//      ushort4 gathers, full 256B row per half-wave) -- doubles gather
//      width for the 4 mid-layer aggs.
// ---------------------------------------------------------------------------

#define IN_F   256
#define HIDW   256          // HEADS*HID
#define CLS    40

typedef __attribute__((ext_vector_type(8))) __bf16 bf16x8;
typedef __attribute__((ext_vector_type(4))) float  f32x4;

__device__ inline bf16x8 zb8() {
    bf16x8 v;
#pragma unroll
    for (int i = 0; i < 8; ++i) v[i] = (__bf16)0.f;
    return v;
}
__device__ inline bf16x8 ldb8(const __hip_bfloat16* p) {
    return *reinterpret_cast<const bf16x8*>(p);
}
__device__ inline float bf2f(unsigned short u) {
    union { unsigned int i; float f; } c;
    c.i = ((unsigned int)u) << 16;
    return c.f;
}
__device__ inline unsigned short f2bu(float f) {
    __hip_bfloat16 t = __float2bfloat16(f);
    union { __hip_bfloat16 b; unsigned short u; } c;
    c.b = t;
    return c.u;
}

// ------------------------------ graph prep --------------------------------
__global__ void k_hist(const int* __restrict__ src, const int* __restrict__ dst,
                       int E, int* __restrict__ outdeg, int* __restrict__ indeg) {
    for (int e = blockIdx.x * blockDim.x + threadIdx.x; e < E; e += gridDim.x * blockDim.x) {
        atomicAdd(&outdeg[src[e]], 1);
        atomicAdd(&indeg[dst[e]], 1);
    }
}

__global__ void k_scan1(const int* __restrict__ cnt, int N, int* __restrict__ rp1,
                        int* __restrict__ bsum) {
    __shared__ int sm[256];
    int i = blockIdx.x * 256 + threadIdx.x;
    int v = (i < N) ? cnt[i] : 0;
    sm[threadIdx.x] = v;
    __syncthreads();
    for (int off = 1; off < 256; off <<= 1) {
        int t = (threadIdx.x >= off) ? sm[threadIdx.x - off] : 0;
        __syncthreads();
        sm[threadIdx.x] += t;
        __syncthreads();
    }
    if (i < N) rp1[i] = sm[threadIdx.x];                  // inclusive within block
    if (threadIdx.x == 255) bsum[blockIdx.x] = sm[255];
}

__global__ void k_scan2(int* __restrict__ bsum, int nb) {
    __shared__ int sm[256];
    int v = (threadIdx.x < nb) ? bsum[threadIdx.x] : 0;
    sm[threadIdx.x] = v;
    __syncthreads();
    for (int off = 1; off < 256; off <<= 1) {
        int t = (threadIdx.x >= off) ? sm[threadIdx.x - off] : 0;
        __syncthreads();
        sm[threadIdx.x] += t;
        __syncthreads();
    }
    if (threadIdx.x < nb) bsum[threadIdx.x] = sm[threadIdx.x] - v;   // exclusive
}

__global__ void k_scan3(int* __restrict__ rp1, const int* __restrict__ bsumExcl, int N) {
    int i = blockIdx.x * 256 + threadIdx.x;
    if (i < N) rp1[i] += bsumExcl[blockIdx.x];
    if (blockIdx.x == 0 && threadIdx.x == 0) rp1[-1] = 0;            // row_ptr[0] = 0
}

__global__ void k_scatter(const int* __restrict__ src, const int* __restrict__ dst,
                          int E, int* __restrict__ cursor, int* __restrict__ csr_src) {
    for (int e = blockIdx.x * blockDim.x + threadIdx.x; e < E; e += gridDim.x * blockDim.x) {
        int d = dst[e];
        int pos = atomicAdd(&cursor[d], 1);
        csr_src[pos] = src[e];
    }
}

__global__ void k_deg(const int* __restrict__ outdeg, const int* __restrict__ indeg,
                      float* __restrict__ oi, float* __restrict__ insq, int N) {
    int i = blockIdx.x * 256 + threadIdx.x;
    if (i < N) {
        int od = outdeg[i]; if (od < 1) od = 1;
        int id = indeg[i];  if (id < 1) id = 1;
        oi[i]   = rsqrtf((float)od);
        insq[i] = sqrtf((float)id);
    }
}

// --------------------------- weight conversion ----------------------------
__global__ void k_cvt6(const float* s0, __hip_bfloat16* d0, int n0,
                       const float* s1, __hip_bfloat16* d1, int n1,
                       const float* s2, __hip_bfloat16* d2, int n2,
                       const float* s3, __hip_bfloat16* d3, int n3,
                       const float* s4, __hip_bfloat16* d4, int n4,
                       const float* s5, __hip_bfloat16* d5, int n5) {
    const float* ss; __hip_bfloat16* dd; int nn;
    switch (blockIdx.y) {
        case 0: ss = s0; dd = d0; nn = n0; break;
        case 1: ss = s1; dd = d1; nn = n1; break;
        case 2: ss = s2; dd = d2; nn = n2; break;
        case 3: ss = s3; dd = d3; nn = n3; break;
        case 4: ss = s4; dd = d4; nn = n4; break;
        default: ss = s5; dd = d5; nn = n5; break;
    }
    for (int i = blockIdx.x * blockDim.x + threadIdx.x; i < nn; i += gridDim.x * blockDim.x)
        dd[i] = __float2bfloat16(ss[i]);
}

// ----- augmented ft weights: rows 0..NF-1 = W, NF+j (j<4)=wl_h, (j<8)=wr_h,
//       NF+8..NF+15 = 0.  wl_h[k] = sum_d W[h*D+d, k]*attn_l[h*D+d] (f32). ---
__global__ void k_prepw(const float* __restrict__ W0,
                        const float* __restrict__ al0, const float* __restrict__ ar0,
                        const float* __restrict__ midW,
                        const float* __restrict__ midal, const float* __restrict__ midar,
                        __hip_bfloat16* __restrict__ Waug0,
                        __hip_bfloat16* __restrict__ midWaug) {
    const int layer = blockIdx.y;
    int NF, K, D;
    const float *W, *al, *ar;
    __hip_bfloat16* dst;
    if (layer == 0) {
        NF = 256; K = 256; D = 64;
        W = W0; al = al0; ar = ar0; dst = Waug0;
    } else {
        const int pg = layer - 1;
        NF = 128; K = 128; D = 32;
        W = midW + pg * 16384; al = midal + pg * 128; ar = midar + pg * 128;
        dst = midWaug + (size_t)pg * 144 * 128;
    }
    const int total = (NF + 16) * K;
    for (int idx = blockIdx.x * 256 + threadIdx.x; idx < total; idx += gridDim.x * 256) {
        const int col = idx / K, k = idx % K;
        float v = 0.f;
        if (col < NF) {
            v = W[(size_t)col * K + k];
        } else {
            const int j = col - NF;
            if (j < 8) {
                const int head = j & 3;
                const float* at = (j < 4) ? al : ar;
                float s = 0.f;
                for (int d = 0; d < D; ++d)
                    s += W[(size_t)(head * D + d) * K + k] * at[head * D + d];
                v = s;
            }
        }
        dst[idx] = __float2bfloat16(v);
    }
}

// ----------------- pipelined LDS-staged GATConv GEMM (K=128/256) ----------
// 512 thr (8 waves), BM=64, 2 tiles/block (grid = ceil(ntiles/2)).
// T14 async-STAGE: next tile's global loads issued into regs before
// compute(t). Waves col-split (ft 0-3 / res 4-7); swapped mfma -> ushort4
// stores; wave0 aug el/er tile.
template<int K, int NF, int NR, int H, bool BN, bool ABF, bool ADDRES>
__global__ __launch_bounds__(512) void k_gatconv_lds(
    const void* __restrict__ Ain, int lda,
    const __hip_bfloat16* __restrict__ Waug,
    const __hip_bfloat16* __restrict__ Wres,
    __hip_bfloat16* __restrict__ ftb, int ldft,
    __hip_bfloat16* __restrict__ hout, int ldh, int houtoff,
    int M, int ntiles,
    const float* __restrict__ scale, const float* __restrict__ shift,
    const float* __restrict__ oi,
    float* __restrict__ el, float* __restrict__ er) {
    constexpr int BM = 64, KF = K / 32, NTOT = NF + NR;
    constexpr int CW = NTOT / 8, CT = CW / 16;
    constexpr int NRT = BM / 16;
    constexpr int CPR = K / 8;            // 8-elem chunks per row
    constexpr int RSTEP = 512 / CPR;      // rows per staging pass
    constexpr int PASS = BM / RSTEP;      // passes per tile
    static_assert(NTOT % 8 == 0 && CW % 16 == 0, "col split");
    static_assert(NF % CW == 0, "ft/res wave boundary");
    static_assert(H == 4, "el/er float4 stores assume H==4");
    __shared__ bf16x8 ldsA[NRT * KF * 64];
    const int tid = threadIdx.x;
    const int wv = tid >> 6, lane = tid & 63, rf = lane & 15, kg = lane >> 4;

    const int c16 = tid % CPR;
    const int ec = c16 * 8;
    const int skf = c16 >> 2, skg = c16 & 3;
    const int srow = tid / CPR;

    float bnsc[8], bnsh[8];
    if (BN) {
        float4 s01 = *reinterpret_cast<const float4*>(scale + ec);
        float4 s23 = *reinterpret_cast<const float4*>(scale + ec + 4);
        float4 h01 = *reinterpret_cast<const float4*>(shift + ec);
        float4 h23 = *reinterpret_cast<const float4*>(shift + ec + 4);
        bnsc[0]=s01.x; bnsc[1]=s01.y; bnsc[2]=s01.z; bnsc[3]=s01.w;
        bnsc[4]=s23.x; bnsc[5]=s23.y; bnsc[6]=s23.z; bnsc[7]=s23.w;
        bnsh[0]=h01.x; bnsh[1]=h01.y; bnsh[2]=h01.z; bnsh[3]=h01.w;
        bnsh[4]=h23.x; bnsh[5]=h23.y; bnsh[6]=h23.z; bnsh[7]=h23.w;
    }

    float4 rA[PASS][2];
    bf16x8 rAb[PASS];

    const bool isft = (wv * CW) < NF;
    const int colbase = isft ? wv * CW : wv * CW - NF;
    const __hip_bfloat16* __restrict__ Wb = isft ? Waug : Wres;

    auto load_regs = [&](int t) {
#pragma unroll
        for (int pz = 0; pz < PASS; ++pz) {
            const int gr = t * BM + pz * RSTEP + srow;
            if (ABF) {
                rAb[pz] = (gr < M)
                    ? ldb8((const __hip_bfloat16*)Ain + (size_t)gr * lda + ec)
                    : zb8();
            } else {
                if (gr < M) {
                    const float* ap = (const float*)Ain + (size_t)gr * lda + ec;
                    rA[pz][0] = *reinterpret_cast<const float4*>(ap);
                    rA[pz][1] = *reinterpret_cast<const float4*>(ap + 4);
                } else {
                    rA[pz][0] = {0.f, 0.f, 0.f, 0.f};
                    rA[pz][1] = {0.f, 0.f, 0.f, 0.f};
                }
            }
        }
    };
    auto write_lds = [&]() {
#pragma unroll
        for (int pz = 0; pz < PASS; ++pz) {
            const int r = pz * RSTEP + srow;
            bf16x8 tv;
            if (ABF) {
                if (BN) {
#pragma unroll
                    for (int i = 0; i < 8; ++i)
                        tv[i] = (__bf16)fmaxf((float)rAb[pz][i] * bnsc[i] + bnsh[i], 0.f);
                } else {
                    tv = rAb[pz];
                }
            } else {
                float v[8] = {rA[pz][0].x, rA[pz][0].y, rA[pz][0].z, rA[pz][0].w,
                              rA[pz][1].x, rA[pz][1].y, rA[pz][1].z, rA[pz][1].w};
#pragma unroll
                for (int i = 0; i < 8; ++i) {
                    float u = v[i];
                    if (BN) u = fmaxf(u * bnsc[i] + bnsh[i], 0.f);
                    tv[i] = (__bf16)u;
                }
            }
            ldsA[((r >> 4) * KF + skf) * 64 + ((skg * 16 + (r & 15)) ^ skf)] = tv;
        }
    };

    int t = blockIdx.x;
    load_regs(t);
    while (t < ntiles) {
        write_lds();
        __syncthreads();
        const int tn = t + gridDim.x;
        if (tn < ntiles) load_regs(tn);     // in flight during compute below

        const int row0 = t * BM;
        for (int ct = 0; ct < CT; ++ct) {
            const int tcol = colbase + ct * 16;
            bf16x8 w[KF];
            const __hip_bfloat16* bp = Wb + (size_t)(tcol + rf) * K + kg * 8;
#pragma unroll
            for (int kf = 0; kf < KF; ++kf) w[kf] = ldb8(bp + kf * 32);
#pragma unroll
            for (int rtp = 0; rtp < NRT / 2; ++rtp) {
                f32x4 acc0 = {0.f, 0.f, 0.f, 0.f};
                f32x4 acc1 = {0.f, 0.f, 0.f, 0.f};
#pragma unroll
                for (int kf = 0; kf < KF; ++kf) {
                    const bf16x8 a0 = ldsA[((2 * rtp) * KF + kf) * 64 + (lane ^ kf)];
                    const bf16x8 a1 = ldsA[((2 * rtp + 1) * KF + kf) * 64 + (lane ^ kf)];
                    acc0 = __builtin_amdgcn_mfma_f32_16x16x32_bf16(w[kf], a0, acc0, 0, 0, 0);
                    acc1 = __builtin_amdgcn_mfma_f32_16x16x32_bf16(w[kf], a1, acc1, 0, 0, 0);
                }
                const int r0g = row0 + 2 * rtp * 16 + rf;
                const int r1g = r0g + 16;
                const int c4 = tcol + 4 * kg;
                ushort4 q0 = {f2bu(acc0[0]), f2bu(acc0[1]), f2bu(acc0[2]), f2bu(acc0[3])};
                ushort4 q1 = {f2bu(acc1[0]), f2bu(acc1[1]), f2bu(acc1[2]), f2bu(acc1[3])};
                if (isft) {
                    if (r0g < M)
                        *reinterpret_cast<ushort4*>(&ftb[(size_t)r0g * ldft + c4]) = q0;
                    if (r1g < M)
                        *reinterpret_cast<ushort4*>(&ftb[(size_t)r1g * ldft + c4]) = q1;
                } else {
                    if (r0g < M) {
                        __hip_bfloat16* hp = hout + (size_t)r0g * ldh + houtoff + c4;
                        if (ADDRES) {
                            ushort4 cur = *reinterpret_cast<ushort4*>(hp);
                            q0.x = f2bu(bf2f(cur.x) + acc0[0]);
                            q0.y = f2bu(bf2f(cur.y) + acc0[1]);
                            q0.z = f2bu(bf2f(cur.z) + acc0[2]);
                            q0.w = f2bu(bf2f(cur.w) + acc0[3]);
                        }
                        *reinterpret_cast<ushort4*>(hp) = q0;
                    }
                    if (r1g < M) {
                        __hip_bfloat16* hp = hout + (size_t)r1g * ldh + houtoff + c4;
                        if (ADDRES) {
                            ushort4 cur = *reinterpret_cast<ushort4*>(hp);
                            q1.x = f2bu(bf2f(cur.x) + acc1[0]);
                            q1.y = f2bu(bf2f(cur.y) + acc1[1]);
                            q1.z = f2bu(bf2f(cur.z) + acc1[2]);
                            q1.w = f2bu(bf2f(cur.w) + acc1[3]);
                        }
                        *reinterpret_cast<ushort4*>(hp) = q1;
                    }
                }
            }
        }

        // ---- aug tile (el/er), wave 0 only ----
        if (wv == 0) {
            bf16x8 w[KF];
            const __hip_bfloat16* bp = Waug + (size_t)(NF + rf) * K + kg * 8;
#pragma unroll
            for (int kf = 0; kf < KF; ++kf) w[kf] = ldb8(bp + kf * 32);
#pragma unroll
            for (int rtp = 0; rtp < NRT / 2; ++rtp) {
                f32x4 acc0 = {0.f, 0.f, 0.f, 0.f};
                f32x4 acc1 = {0.f, 0.f, 0.f, 0.f};
#pragma unroll
                for (int kf = 0; kf < KF; ++kf) {
                    const bf16x8 a0 = ldsA[((2 * rtp) * KF + kf) * 64 + (lane ^ kf)];
                    const bf16x8 a1 = ldsA[((2 * rtp + 1) * KF + kf) * 64 + (lane ^ kf)];
                    acc0 = __builtin_amdgcn_mfma_f32_16x16x32_bf16(w[kf], a0, acc0, 0, 0, 0);
                    acc1 = __builtin_amdgcn_mfma_f32_16x16x32_bf16(w[kf], a1, acc1, 0, 0, 0);
                }
                const int r0g = row0 + 2 * rtp * 16 + rf;
                const int r1g = r0g + 16;
                if (kg == 0) {
                    if (r0g < M) {
                        const float o = oi[r0g];
                        float4 v = {acc0[0] * o, acc0[1] * o, acc0[2] * o, acc0[3] * o};
                        *reinterpret_cast<float4*>(&el[(size_t)r0g * 4]) = v;
                    }
                    if (r1g < M) {
                        const float o = oi[r1g];
                        float4 v = {acc1[0] * o, acc1[1] * o, acc1[2] * o, acc1[3] * o};
                        *reinterpret_cast<float4*>(&el[(size_t)r1g * 4]) = v;
                    }
                } else if (kg == 1) {
                    if (r0g < M) {
                        float4 v = {acc0[0], acc0[1], acc0[2], acc0[3]};
                        *reinterpret_cast<float4*>(&er[(size_t)r0g * 4]) = v;
                    }
                    if (r1g < M) {
                        float4 v = {acc1[0], acc1[1], acc1[2], acc1[3]};
                        *reinterpret_cast<float4*>(&er[(size_t)r1g * 4]) = v;
                    }
                }
            }
        }
        __syncthreads();        // LDS safe to overwrite next iteration
        t = tn;
    }
}

// -------- small merged GATConv (last layer, NOUT=40), bf16 A -------------
template<int K, int NF, int NR, int H>
__global__ __launch_bounds__(256) void k_gatconv_sm(
    const __hip_bfloat16* __restrict__ A, int lda,
    const __hip_bfloat16* __restrict__ Wft,
    const __hip_bfloat16* __restrict__ Wres,
    __hip_bfloat16* __restrict__ ftb, int ldft,
    float* __restrict__ Cres, int ldcres,
    int M,
    const float* __restrict__ scale, const float* __restrict__ shift,
    const float* __restrict__ bias,
    const float* __restrict__ attn_l, const float* __restrict__ attn_r,
    const float* __restrict__ oi,
    float* __restrict__ el, float* __restrict__ er) {
    constexpr int KF   = K / 32;
    constexpr int NCTF = (NF + 15) / 16;
    constexpr int NCTR = (NR + 15) / 16;
    constexpr int CTH  = NCTF / H;
    static_assert(NCTF % H == 0, "head tiling");
    const int wave = threadIdx.x >> 6, lane = threadIdx.x & 63;
    const int row0 = blockIdx.x * 64 + wave * 16;
    const int rf = lane & 15, kg = lane >> 4;

    bf16x8 a[KF];
    {
        const int row = row0 + rf;
        const bool rok = row < M;
#pragma unroll
        for (int kf = 0; kf < KF; ++kf) {
            const int c0 = kg * 8 + kf * 32;
            if (rok) {
                bf16x8 raw = ldb8(A + (size_t)row * lda + c0);
                float4 s01 = *reinterpret_cast<const float4*>(scale + c0);
                float4 s23 = *reinterpret_cast<const float4*>(scale + c0 + 4);
                float4 h01 = *reinterpret_cast<const float4*>(shift + c0);
                float4 h23 = *reinterpret_cast<const float4*>(shift + c0 + 4);
                float sc[8] = {s01.x,s01.y,s01.z,s01.w,s23.x,s23.y,s23.z,s23.w};
                float sh[8] = {h01.x,h01.y,h01.z,h01.w,h23.x,h23.y,h23.z,h23.w};
                bf16x8 t;
#pragma unroll
                for (int i = 0; i < 8; ++i)
                    t[i] = (__bf16)fmaxf((float)raw[i] * sc[i] + sh[i], 0.f);
                a[kf] = t;
            } else {
                a[kf] = zb8();
            }
        }
    }

    int ct = 0;
    for (int hh = 0; hh < H; ++hh) {
        float elp[4] = {0.f, 0.f, 0.f, 0.f};
        float erp[4] = {0.f, 0.f, 0.f, 0.f};
        for (int cth = 0; cth < CTH; ++cth, ++ct) {
            const int ccol = ct * 16 + rf;
            bf16x8 b[KF];
            const __hip_bfloat16* bp = Wft + (size_t)ccol * K + kg * 8;
#pragma unroll
            for (int kf = 0; kf < KF; ++kf)
                b[kf] = (ccol < NF) ? ldb8(bp + kf * 32) : zb8();
            f32x4 acc = {0.f, 0.f, 0.f, 0.f};
#pragma unroll
            for (int kf = 0; kf < KF; ++kf)
                acc = __builtin_amdgcn_mfma_f32_16x16x32_bf16(a[kf], b[kf], acc, 0, 0, 0);
            float al = 0.f, ar = 0.f;
            if (ccol < NF) { al = attn_l[ccol]; ar = attn_r[ccol]; }
            if (ccol < NF) {
#pragma unroll
                for (int r = 0; r < 4; ++r) {
                    const float v = acc[r];
                    elp[r] += v * al; erp[r] += v * ar;
                    const int row = row0 + kg * 4 + r;
                    if (row < M)
                        ftb[(size_t)row * ldft + ccol] = __float2bfloat16(v);
                }
            }
        }
#pragma unroll
        for (int off = 1; off <= 8; off <<= 1)
#pragma unroll
            for (int r = 0; r < 4; ++r) {
                elp[r] += __shfl_xor(elp[r], off);
                erp[r] += __shfl_xor(erp[r], off);
            }
        if (rf == 0) {
#pragma unroll
            for (int r = 0; r < 4; ++r) {
                const int row = row0 + kg * 4 + r;
                if (row < M) {
                    el[(size_t)row * H + hh] = oi[row] * elp[r];
                    er[(size_t)row * H + hh] = erp[r];
                }
            }
        }
    }

    for (int rt = 0; rt < NCTR; ++rt) {
        const int ccol = rt * 16 + rf;
        bf16x8 b[KF];
        const __hip_bfloat16* bp = Wres + (size_t)ccol * K + kg * 8;
#pragma unroll
        for (int kf = 0; kf < KF; ++kf)
            b[kf] = (ccol < NR) ? ldb8(bp + kf * 32) : zb8();
        f32x4 acc = {0.f, 0.f, 0.f, 0.f};
#pragma unroll
        for (int kf = 0; kf < KF; ++kf)
            acc = __builtin_amdgcn_mfma_f32_16x16x32_bf16(a[kf], b[kf], acc, 0, 0, 0);
        if (ccol < NR) {
#pragma unroll
            for (int r = 0; r < 4; ++r) {
                const int row = row0 + kg * 4 + r;
                if (row < M) {
                    float v = acc[r];
                    if (bias) v += bias[ccol];
                    Cres[(size_t)row * ldcres + ccol] = v;
                }
            }
        }
    }
}

// ------------- fused edge softmax + message aggregation (per dst) ---------
template<int EPL>
__device__ inline void ldrow(const __hip_bfloat16* fp, float* f) {
    if constexpr (EPL == 4) {
        ushort4 q = *reinterpret_cast<const ushort4*>(fp);
        f[0] = bf2f(q.x); f[1] = bf2f(q.y); f[2] = bf2f(q.z); f[3] = bf2f(q.w);
    } else if constexpr (EPL == 2) {
        ushort2 q = *reinterpret_cast<const ushort2*>(fp);
        f[0] = bf2f(q.x); f[1] = bf2f(q.y);
    } else {
        f[0] = bf2f(*reinterpret_cast<const unsigned short*>(fp));
    }
}
__device__ inline float escore(float sc) {
    sc = sc >= 0.f ? sc : 0.2f * sc;
    sc = fminf(fmaxf(sc, -30.f), 30.f);
    return __expf(sc);
}

// LW = lanes per node (64 or 32). 256 thr -> 256/LW nodes per block.
// EPL = W/LW elements per lane (>=1). OBF: out is bf16 (RMW); else f32.
template<int H, int D, int LW, bool OBF>
__global__ __launch_bounds__(256) void k_agg(
    const __hip_bfloat16* __restrict__ ftb,
    const float* __restrict__ el, const float* __restrict__ er,
    const int* __restrict__ row_ptr, const int* __restrict__ csr_src,
    const float* __restrict__ oi, const float* __restrict__ insq,
    void* __restrict__ out, int ldc, int N) {
    constexpr int W = H * D;
    constexpr int EPL = (W >= LW) ? (W / LW) : 1;
    constexpr int NPB = 256 / LW;
    const int lane = threadIdx.x % LW;
    const int v = blockIdx.x * NPB + (threadIdx.x / LW);
    if (v >= N) return;
    if (W < LW && lane >= W) return;
    const int col0 = lane * EPL;
    const int myh = (W >= LW) ? (col0 / D) : 0;
    const int s = row_ptr[v], e = row_ptr[v + 1];
    const float erv = er[(size_t)v * H + myh];

    float denom = 0.f;
    float acc[EPL];
#pragma unroll
    for (int k = 0; k < EPL; ++k) acc[k] = 0.f;

    int p = s;
    for (; p + 3 < e; p += 4) {
        const int u0 = csr_src[p + 0], u1 = csr_src[p + 1];
        const int u2 = csr_src[p + 2], u3 = csr_src[p + 3];
        float f0[EPL], f1[EPL], f2[EPL], f3[EPL];
        ldrow<EPL>(ftb + (size_t)u0 * W + col0, f0);
        ldrow<EPL>(ftb + (size_t)u1 * W + col0, f1);
        ldrow<EPL>(ftb + (size_t)u2 * W + col0, f2);
        ldrow<EPL>(ftb + (size_t)u3 * W + col0, f3);
        const float s0 = el[(size_t)u0 * H + myh], s1 = el[(size_t)u1 * H + myh];
        const float s2 = el[(size_t)u2 * H + myh], s3 = el[(size_t)u3 * H + myh];
        const float o0 = oi[u0], o1 = oi[u1], o2 = oi[u2], o3 = oi[u3];
        const float w0 = escore(s0 + erv), w1 = escore(s1 + erv);
        const float w2 = escore(s2 + erv), w3 = escore(s3 + erv);
        denom += (w0 + w1) + (w2 + w3);
        const float a0 = w0 * o0, a1 = w1 * o1, a2 = w2 * o2, a3 = w3 * o3;
#pragma unroll
        for (int k = 0; k < EPL; ++k)
            acc[k] += a0 * f0[k] + a1 * f1[k] + a2 * f2[k] + a3 * f3[k];
    }
    for (; p < e; ++p) {
        const int u = csr_src[p];
        float f[EPL];
        ldrow<EPL>(ftb + (size_t)u * W + col0, f);
        const float w = escore(el[(size_t)u * H + myh] + erv);
        denom += w;
        const float a = w * oi[u];
#pragma unroll
        for (int k = 0; k < EPL; ++k) acc[k] += a * f[k];
    }

    const float iv = insq[v] / fmaxf(denom, 1e-9f);
    if (OBF) {
        __hip_bfloat16* op = (__hip_bfloat16*)out + (size_t)v * ldc + col0;
        if constexpr (EPL == 4) {
            ushort4 o = *reinterpret_cast<ushort4*>(op);
            o.x = f2bu(bf2f(o.x) + iv * acc[0]);
            o.y = f2bu(bf2f(o.y) + iv * acc[1]);
            o.z = f2bu(bf2f(o.z) + iv * acc[2]);
            o.w = f2bu(bf2f(o.w) + iv * acc[3]);
            *reinterpret_cast<ushort4*>(op) = o;
        } else if constexpr (EPL == 2) {
            ushort2 o = *reinterpret_cast<ushort2*>(op);
            o.x = f2bu(bf2f(o.x) + iv * acc[0]);
            o.y = f2bu(bf2f(o.y) + iv * acc[1]);
            *reinterpret_cast<ushort2*>(op) = o;
        } else {
            unsigned short* up = (unsigned short*)op;
            *up = f2bu(bf2f(*up) + iv * acc[0]);
        }
    } else {
        float* op = (float*)out + (size_t)v * ldc + col0;
        if constexpr (EPL == 4) {
            float4 o = *reinterpret_cast<float4*>(op);
            o.x += iv * acc[0]; o.y += iv * acc[1]; o.z += iv * acc[2]; o.w += iv * acc[3];
            *reinterpret_cast<float4*>(op) = o;
        } else if constexpr (EPL == 2) {
            float2 o = *reinterpret_cast<float2*>(op);
            o.x += iv * acc[0]; o.y += iv * acc[1];
            *reinterpret_cast<float2*>(op) = o;
        } else {
            op[0] += iv * acc[0];
        }
    }
}

// ------------------------------ batch norm (bf16 input) -------------------
template<int F>
__global__ __launch_bounds__(256) void k_bn_part(const __hip_bfloat16* __restrict__ in,
                                                 int ldin, int N,
                                                 float* __restrict__ psum,
                                                 float* __restrict__ psum2) {
    constexpr int CP = F / 2;                 // col pairs
    constexpr int SL = 256 / CP;              // rows per block pass
    const int cp = threadIdx.x % CP;
    const int pr = blockIdx.x * SL + threadIdx.x / CP;
    const int PRT = gridDim.x * SL;
    float s0 = 0.f, s20 = 0.f, s1 = 0.f, s21 = 0.f;
    for (int r = pr; r < N; r += PRT) {
        ushort2 q = *reinterpret_cast<const ushort2*>(&in[(size_t)r * ldin + cp * 2]);
        const float a = bf2f(q.x), b = bf2f(q.y);
        s0 += a; s20 += a * a; s1 += b; s21 += b * b;
    }
    psum[(size_t)pr * F + cp * 2] = s0;
    psum[(size_t)pr * F + cp * 2 + 1] = s1;
    psum2[(size_t)pr * F + cp * 2] = s20;
    psum2[(size_t)pr * F + cp * 2 + 1] = s21;
}

template<int F>
__global__ __launch_bounds__(256) void k_bn_fin(const float* __restrict__ psum,
                                                const float* __restrict__ psum2, int PRT,
                                                const float* __restrict__ gamma,
                                                const float* __restrict__ beta,
                                                float* __restrict__ scale,
                                                float* __restrict__ shift, int N) {
    const int col = blockIdx.x;
    float s = 0.f, s2 = 0.f;
    for (int p = threadIdx.x; p < PRT; p += 256) {
        s += psum[(size_t)p * F + col];
        s2 += psum2[(size_t)p * F + col];
    }
#pragma unroll
    for (int off = 32; off; off >>= 1) {
        s += __shfl_down(s, off);
        s2 += __shfl_down(s2, off);
    }
    __shared__ float sm[4], sm2[4];
    const int wave = threadIdx.x >> 6, lane = threadIdx.x & 63;
    if (lane == 0) { sm[wave] = s; sm2[wave] = s2; }
    __syncthreads();
    if (threadIdx.x == 0) {
        s = sm[0] + sm[1] + sm[2] + sm[3];
        s2 = sm2[0] + sm2[1] + sm2[2] + sm2[3];
        float mu = s / N;
        float var = s2 / N - mu * mu;
        float isd = rsqrtf(var + 1e-5f);
        float g = gamma[col];
        scale[col] = g * isd;
        shift[col] = beta[col] - g * isd * mu;
    }
}

// ------------------------------- launcher ---------------------------------
extern "C" void kernel_launch(void* const* d_in, const int* in_sizes, int n_in,
                              void* d_out, int out_size, void* d_ws, size_t ws_size,
                              hipStream_t stream) {
    const float* x           = (const float*)d_in[0];
    const int*   src         = (const int*)d_in[1];
    const int*   dst         = (const int*)d_in[2];
    const float* W0          = (const float*)d_in[3];
    const float* attn_l0     = (const float*)d_in[4];
    const float* attn_r0     = (const float*)d_in[5];
    const float* resW0       = (const float*)d_in[6];
    const float* mid_bn_g    = (const float*)d_in[7];
    const float* mid_bn_b    = (const float*)d_in[8];
    const float* mid_W       = (const float*)d_in[9];
    const float* mid_attn_l  = (const float*)d_in[10];
    const float* mid_attn_r  = (const float*)d_in[11];
    const float* mid_resW    = (const float*)d_in[12];
    const float* norm_gamma  = (const float*)d_in[13];
    const float* norm_beta   = (const float*)d_in[14];
    const float* W_last      = (const float*)d_in[15];
    const float* attn_l_last = (const float*)d_in[16];
    const float* attn_r_last = (const float*)d_in[17];
    const float* resW_last   = (const float*)d_in[18];
    const float* bias_last   = (const float*)d_in[19];

    const int N = in_sizes[0] / IN_F;
    const int E = in_sizes[1];

    // ---- workspace carve-up (256B aligned) ----
    char* p = (char*)d_ws;
    size_t used = 0;
    auto take = [&](size_t bytes) -> char* {
        char* r = p;
        size_t adv = (bytes + 255) & ~(size_t)255;
        p += adv; used += adv;
        return r;
    };
    __hip_bfloat16* h       = (__hip_bfloat16*)take((size_t)N * HIDW * 2);
    __hip_bfloat16* ftb     = (__hip_bfloat16*)take((size_t)N * HIDW * 2);
    float*          el      = (float*)take((size_t)N * 4 * 4);
    float*          er      = (float*)take((size_t)N * 4 * 4);
    float*          oi      = (float*)take((size_t)N * 4);
    float*          insq    = (float*)take((size_t)N * 4);
    int*            indeg   = (int*)take((size_t)N * 4);
    int*            outdeg  = (int*)take((size_t)N * 4);
    int*            row_ptr = (int*)take((size_t)(N + 1) * 4);
    int*            cursor  = (int*)take((size_t)N * 4);
    int*            csr_src = (int*)take((size_t)E * 4);
    int*            bsum    = (int*)take(256 * 4);
    float*          psum    = (float*)take(1 << 20);
    float*          psum2   = (float*)take(1 << 20);
    float*          scale   = (float*)take(1024);
    float*          shift   = (float*)take(1024);
    __hip_bfloat16* Waug0     = (__hip_bfloat16*)take((size_t)272 * 256 * 2);
    __hip_bfloat16* midWaug   = (__hip_bfloat16*)take((size_t)4 * 144 * 128 * 2);
    __hip_bfloat16* resW0bf   = (__hip_bfloat16*)take(65536 * 2);
    __hip_bfloat16* midresWbf = (__hip_bfloat16*)take(65536 * 2);
    __hip_bfloat16* Wlastbf   = (__hip_bfloat16*)take(10240 * 2);
    __hip_bfloat16* resWlastbf= (__hip_bfloat16*)take(10240 * 2);
    if (used > ws_size) return;   // out of workspace: leave output poisoned (visible failure)

    const int nbN = (N + 255) / 256;
    const int NB4 = (N + 3) / 4;
    const int NB8 = (N + 7) / 8;
    const int NT  = (N + 63) / 64;              // GEMM row-tiles (BM=64)
    const int GWP = (NT + 1) / 2;               // pipelined: 2 tiles/block
    const int GWS = (N + 63) / 64;              // small kernel: 64 rows/block
    const int BNB = 512;                        // BN partial blocks

    // ---- graph prep ----
    hipMemsetAsync(indeg, 0, (size_t)N * 4, stream);
    hipMemsetAsync(outdeg, 0, (size_t)N * 4, stream);
    k_hist<<<1024, 256, 0, stream>>>(src, dst, E, outdeg, indeg);
    k_scan1<<<nbN, 256, 0, stream>>>(indeg, N, row_ptr + 1, bsum);
    k_scan2<<<1, 256, 0, stream>>>(bsum, nbN);
    k_scan3<<<nbN, 256, 0, stream>>>(row_ptr + 1, bsum, N);
    hipMemcpyAsync(cursor, row_ptr, (size_t)N * 4, hipMemcpyDeviceToDevice, stream);
    k_scatter<<<1024, 256, 0, stream>>>(src, dst, E, cursor, csr_src);
    k_deg<<<nbN, 256, 0, stream>>>(outdeg, indeg, oi, insq, N);

    // ---- weight conversion + augmentation ----
    k_cvt6<<<dim3(64, 4), 256, 0, stream>>>(resW0, resW0bf, 65536,
                                            mid_resW, midresWbf, 65536,
                                            W_last, Wlastbf, 10240,
                                            resW_last, resWlastbf, 10240,
                                            nullptr, nullptr, 0,
                                            nullptr, nullptr, 0);
    k_prepw<<<dim3(96, 5), 256, 0, stream>>>(W0, attn_l0, attn_r0,
                                             mid_W, mid_attn_l, mid_attn_r,
                                             Waug0, midWaug);

    // ---- layer 0: GATConv(256 -> 4x64), A = x (f32, no BN) ----
    k_gatconv_lds<256, 256, 256, 4, false, false, false><<<GWP, 512, 0, stream>>>(
        x, 256, Waug0, resW0bf, ftb, 256, h, 256, 0, N, NT,
        nullptr, nullptr, oi, el, er);
    k_agg<4, 64, 64, true><<<NB4, 256, 0, stream>>>(ftb, el, er, row_ptr, csr_src,
                                                    oi, insq, h, 256, N);

    // ---- reversible middle layers ----
    for (int l = 0; l < 2; ++l) {
        for (int g = 0; g < 2; ++g) {
            const int inoff  = (g == 0) ? 128 : 0;
            const int outoff = (g == 0) ? 0 : 128;
            const int pg = l * 2 + g;
            k_bn_part<128><<<BNB, 256, 0, stream>>>(h + inoff, 256, N, psum, psum2);
            k_bn_fin<128><<<128, 256, 0, stream>>>(psum, psum2, BNB * 4,
                                                   mid_bn_g + pg * 128, mid_bn_b + pg * 128,
                                                   scale, shift, N);
            k_gatconv_lds<128, 128, 128, 4, true, true, true><<<GWP, 512, 0, stream>>>(
                h + inoff, 256, midWaug + (size_t)pg * 144 * 128, midresWbf + pg * 16384,
                ftb, 128, h, 256, outoff, N, NT,
                scale, shift, oi, el, er);
            k_agg<4, 32, 32, true><<<NB8, 256, 0, stream>>>(ftb, el, er, row_ptr, csr_src,
                                                            oi, insq, h + outoff, 256, N);
        }
    }

    // ---- final norm + GATConv(256 -> 1x40) + bias ----
    k_bn_part<256><<<BNB, 256, 0, stream>>>(h, 256, N, psum, psum2);
    k_bn_fin<256><<<256, 256, 0, stream>>>(psum, psum2, BNB * 2, norm_gamma, norm_beta,
                                           scale, shift, N);
    k_gatconv_sm<256, 40, 40, 1><<<GWS, 256, 0, stream>>>(
        h, 256, Wlastbf, resWlastbf, ftb, 40, (float*)d_out, 40, N,
        scale, shift, bias_last,
        attn_l_last, attn_r_last, oi, el, er);
    k_agg<1, 40, 64, false><<<NB4, 256, 0, stream>>>(ftb, el, er, row_ptr, csr_src,
                                                     oi, insq, (float*)d_out, 40, N);
}

// Round 17
// 527.053 us; speedup vs baseline: 1.1261x; 1.0154x over previous
//
#include <hip/hip_runtime.h>
#include <hip/hip_bf16.h>

// ---------------------------------------------------------------------------
// RevGAT forward on MI355X.
// R2-R4: BN widened, k_agg single-pass, big fusion (706us).
// R5/R6/R10: col-split replication / no-LDS / 4-wave REGRESSED.
// R7-R9: LDS 8-wave col-split, swapped MFMA, el/er aug cols (581us).
// R11/R12: BM=32 queue + bf16 h (559us). R13: BN-fused agg REGRESSED.
// R14/R15: R9 geometry + bf16 h + T14 pipeline (556us). GEMM closed ~67us.
// R16: k_agg LW=32 for mids (8B/lane) -> 535us (-21, as predicted).
// R17: extend the verified gather-width lever: L0 agg LW=32 (16B/lane via
//      bf16x8), mid aggs LW=16 (16B/lane). Final W=40 agg unchanged.
// ---------------------------------------------------------------------------

#define IN_F   256
#define HIDW   256          // HEADS*HID
#define CLS    40

typedef __attribute__((ext_vector_type(8))) __bf16 bf16x8;
typedef __attribute__((ext_vector_type(4))) float  f32x4;

__device__ inline bf16x8 zb8() {
    bf16x8 v;
#pragma unroll
    for (int i = 0; i < 8; ++i) v[i] = (__bf16)0.f;
    return v;
}
__device__ inline bf16x8 ldb8(const __hip_bfloat16* p) {
    return *reinterpret_cast<const bf16x8*>(p);
}
__device__ inline float bf2f(unsigned short u) {
    union { unsigned int i; float f; } c;
    c.i = ((unsigned int)u) << 16;
    return c.f;
}
__device__ inline unsigned short f2bu(float f) {
    __hip_bfloat16 t = __float2bfloat16(f);
    union { __hip_bfloat16 b; unsigned short u; } c;
    c.b = t;
    return c.u;
}

// ------------------------------ graph prep --------------------------------
__global__ void k_hist(const int* __restrict__ src, const int* __restrict__ dst,
                       int E, int* __restrict__ outdeg, int* __restrict__ indeg) {
    for (int e = blockIdx.x * blockDim.x + threadIdx.x; e < E; e += gridDim.x * blockDim.x) {
        atomicAdd(&outdeg[src[e]], 1);
        atomicAdd(&indeg[dst[e]], 1);
    }
}

__global__ void k_scan1(const int* __restrict__ cnt, int N, int* __restrict__ rp1,
                        int* __restrict__ bsum) {
    __shared__ int sm[256];
    int i = blockIdx.x * 256 + threadIdx.x;
    int v = (i < N) ? cnt[i] : 0;
    sm[threadIdx.x] = v;
    __syncthreads();
    for (int off = 1; off < 256; off <<= 1) {
        int t = (threadIdx.x >= off) ? sm[threadIdx.x - off] : 0;
        __syncthreads();
        sm[threadIdx.x] += t;
        __syncthreads();
    }
    if (i < N) rp1[i] = sm[threadIdx.x];                  // inclusive within block
    if (threadIdx.x == 255) bsum[blockIdx.x] = sm[255];
}

__global__ void k_scan2(int* __restrict__ bsum, int nb) {
    __shared__ int sm[256];
    int v = (threadIdx.x < nb) ? bsum[threadIdx.x] : 0;
    sm[threadIdx.x] = v;
    __syncthreads();
    for (int off = 1; off < 256; off <<= 1) {
        int t = (threadIdx.x >= off) ? sm[threadIdx.x - off] : 0;
        __syncthreads();
        sm[threadIdx.x] += t;
        __syncthreads();
    }
    if (threadIdx.x < nb) bsum[threadIdx.x] = sm[threadIdx.x] - v;   // exclusive
}

__global__ void k_scan3(int* __restrict__ rp1, const int* __restrict__ bsumExcl, int N) {
    int i = blockIdx.x * 256 + threadIdx.x;
    if (i < N) rp1[i] += bsumExcl[blockIdx.x];
    if (blockIdx.x == 0 && threadIdx.x == 0) rp1[-1] = 0;            // row_ptr[0] = 0
}

__global__ void k_scatter(const int* __restrict__ src, const int* __restrict__ dst,
                          int E, int* __restrict__ cursor, int* __restrict__ csr_src) {
    for (int e = blockIdx.x * blockDim.x + threadIdx.x; e < E; e += gridDim.x * blockDim.x) {
        int d = dst[e];
        int pos = atomicAdd(&cursor[d], 1);
        csr_src[pos] = src[e];
    }
}

__global__ void k_deg(const int* __restrict__ outdeg, const int* __restrict__ indeg,
                      float* __restrict__ oi, float* __restrict__ insq, int N) {
    int i = blockIdx.x * 256 + threadIdx.x;
    if (i < N) {
        int od = outdeg[i]; if (od < 1) od = 1;
        int id = indeg[i];  if (id < 1) id = 1;
        oi[i]   = rsqrtf((float)od);
        insq[i] = sqrtf((float)id);
    }
}

// --------------------------- weight conversion ----------------------------
__global__ void k_cvt6(const float* s0, __hip_bfloat16* d0, int n0,
                       const float* s1, __hip_bfloat16* d1, int n1,
                       const float* s2, __hip_bfloat16* d2, int n2,
                       const float* s3, __hip_bfloat16* d3, int n3,
                       const float* s4, __hip_bfloat16* d4, int n4,
                       const float* s5, __hip_bfloat16* d5, int n5) {
    const float* ss; __hip_bfloat16* dd; int nn;
    switch (blockIdx.y) {
        case 0: ss = s0; dd = d0; nn = n0; break;
        case 1: ss = s1; dd = d1; nn = n1; break;
        case 2: ss = s2; dd = d2; nn = n2; break;
        case 3: ss = s3; dd = d3; nn = n3; break;
        case 4: ss = s4; dd = d4; nn = n4; break;
        default: ss = s5; dd = d5; nn = n5; break;
    }
    for (int i = blockIdx.x * blockDim.x + threadIdx.x; i < nn; i += gridDim.x * blockDim.x)
        dd[i] = __float2bfloat16(ss[i]);
}

// ----- augmented ft weights: rows 0..NF-1 = W, NF+j (j<4)=wl_h, (j<8)=wr_h,
//       NF+8..NF+15 = 0.  wl_h[k] = sum_d W[h*D+d, k]*attn_l[h*D+d] (f32). ---
__global__ void k_prepw(const float* __restrict__ W0,
                        const float* __restrict__ al0, const float* __restrict__ ar0,
                        const float* __restrict__ midW,
                        const float* __restrict__ midal, const float* __restrict__ midar,
                        __hip_bfloat16* __restrict__ Waug0,
                        __hip_bfloat16* __restrict__ midWaug) {
    const int layer = blockIdx.y;
    int NF, K, D;
    const float *W, *al, *ar;
    __hip_bfloat16* dst;
    if (layer == 0) {
        NF = 256; K = 256; D = 64;
        W = W0; al = al0; ar = ar0; dst = Waug0;
    } else {
        const int pg = layer - 1;
        NF = 128; K = 128; D = 32;
        W = midW + pg * 16384; al = midal + pg * 128; ar = midar + pg * 128;
        dst = midWaug + (size_t)pg * 144 * 128;
    }
    const int total = (NF + 16) * K;
    for (int idx = blockIdx.x * 256 + threadIdx.x; idx < total; idx += gridDim.x * 256) {
        const int col = idx / K, k = idx % K;
        float v = 0.f;
        if (col < NF) {
            v = W[(size_t)col * K + k];
        } else {
            const int j = col - NF;
            if (j < 8) {
                const int head = j & 3;
                const float* at = (j < 4) ? al : ar;
                float s = 0.f;
                for (int d = 0; d < D; ++d)
                    s += W[(size_t)(head * D + d) * K + k] * at[head * D + d];
                v = s;
            }
        }
        dst[idx] = __float2bfloat16(v);
    }
}

// ----------------- pipelined LDS-staged GATConv GEMM (K=128/256) ----------
// 512 thr (8 waves), BM=64, 2 tiles/block (grid = ceil(ntiles/2)).
// T14 async-STAGE: next tile's global loads issued into regs before
// compute(t). Waves col-split (ft 0-3 / res 4-7); swapped mfma -> ushort4
// stores; wave0 aug el/er tile.
template<int K, int NF, int NR, int H, bool BN, bool ABF, bool ADDRES>
__global__ __launch_bounds__(512) void k_gatconv_lds(
    const void* __restrict__ Ain, int lda,
    const __hip_bfloat16* __restrict__ Waug,
    const __hip_bfloat16* __restrict__ Wres,
    __hip_bfloat16* __restrict__ ftb, int ldft,
    __hip_bfloat16* __restrict__ hout, int ldh, int houtoff,
    int M, int ntiles,
    const float* __restrict__ scale, const float* __restrict__ shift,
    const float* __restrict__ oi,
    float* __restrict__ el, float* __restrict__ er) {
    constexpr int BM = 64, KF = K / 32, NTOT = NF + NR;
    constexpr int CW = NTOT / 8, CT = CW / 16;
    constexpr int NRT = BM / 16;
    constexpr int CPR = K / 8;            // 8-elem chunks per row
    constexpr int RSTEP = 512 / CPR;      // rows per staging pass
    constexpr int PASS = BM / RSTEP;      // passes per tile
    static_assert(NTOT % 8 == 0 && CW % 16 == 0, "col split");
    static_assert(NF % CW == 0, "ft/res wave boundary");
    static_assert(H == 4, "el/er float4 stores assume H==4");
    __shared__ bf16x8 ldsA[NRT * KF * 64];
    const int tid = threadIdx.x;
    const int wv = tid >> 6, lane = tid & 63, rf = lane & 15, kg = lane >> 4;

    const int c16 = tid % CPR;
    const int ec = c16 * 8;
    const int skf = c16 >> 2, skg = c16 & 3;
    const int srow = tid / CPR;

    float bnsc[8], bnsh[8];
    if (BN) {
        float4 s01 = *reinterpret_cast<const float4*>(scale + ec);
        float4 s23 = *reinterpret_cast<const float4*>(scale + ec + 4);
        float4 h01 = *reinterpret_cast<const float4*>(shift + ec);
        float4 h23 = *reinterpret_cast<const float4*>(shift + ec + 4);
        bnsc[0]=s01.x; bnsc[1]=s01.y; bnsc[2]=s01.z; bnsc[3]=s01.w;
        bnsc[4]=s23.x; bnsc[5]=s23.y; bnsc[6]=s23.z; bnsc[7]=s23.w;
        bnsh[0]=h01.x; bnsh[1]=h01.y; bnsh[2]=h01.z; bnsh[3]=h01.w;
        bnsh[4]=h23.x; bnsh[5]=h23.y; bnsh[6]=h23.z; bnsh[7]=h23.w;
    }

    float4 rA[PASS][2];
    bf16x8 rAb[PASS];

    const bool isft = (wv * CW) < NF;
    const int colbase = isft ? wv * CW : wv * CW - NF;
    const __hip_bfloat16* __restrict__ Wb = isft ? Waug : Wres;

    auto load_regs = [&](int t) {
#pragma unroll
        for (int pz = 0; pz < PASS; ++pz) {
            const int gr = t * BM + pz * RSTEP + srow;
            if (ABF) {
                rAb[pz] = (gr < M)
                    ? ldb8((const __hip_bfloat16*)Ain + (size_t)gr * lda + ec)
                    : zb8();
            } else {
                if (gr < M) {
                    const float* ap = (const float*)Ain + (size_t)gr * lda + ec;
                    rA[pz][0] = *reinterpret_cast<const float4*>(ap);
                    rA[pz][1] = *reinterpret_cast<const float4*>(ap + 4);
                } else {
                    rA[pz][0] = {0.f, 0.f, 0.f, 0.f};
                    rA[pz][1] = {0.f, 0.f, 0.f, 0.f};
                }
            }
        }
    };
    auto write_lds = [&]() {
#pragma unroll
        for (int pz = 0; pz < PASS; ++pz) {
            const int r = pz * RSTEP + srow;
            bf16x8 tv;
            if (ABF) {
                if (BN) {
#pragma unroll
                    for (int i = 0; i < 8; ++i)
                        tv[i] = (__bf16)fmaxf((float)rAb[pz][i] * bnsc[i] + bnsh[i], 0.f);
                } else {
                    tv = rAb[pz];
                }
            } else {
                float v[8] = {rA[pz][0].x, rA[pz][0].y, rA[pz][0].z, rA[pz][0].w,
                              rA[pz][1].x, rA[pz][1].y, rA[pz][1].z, rA[pz][1].w};
#pragma unroll
                for (int i = 0; i < 8; ++i) {
                    float u = v[i];
                    if (BN) u = fmaxf(u * bnsc[i] + bnsh[i], 0.f);
                    tv[i] = (__bf16)u;
                }
            }
            ldsA[((r >> 4) * KF + skf) * 64 + ((skg * 16 + (r & 15)) ^ skf)] = tv;
        }
    };

    int t = blockIdx.x;
    load_regs(t);
    while (t < ntiles) {
        write_lds();
        __syncthreads();
        const int tn = t + gridDim.x;
        if (tn < ntiles) load_regs(tn);     // in flight during compute below

        const int row0 = t * BM;
        for (int ct = 0; ct < CT; ++ct) {
            const int tcol = colbase + ct * 16;
            bf16x8 w[KF];
            const __hip_bfloat16* bp = Wb + (size_t)(tcol + rf) * K + kg * 8;
#pragma unroll
            for (int kf = 0; kf < KF; ++kf) w[kf] = ldb8(bp + kf * 32);
#pragma unroll
            for (int rtp = 0; rtp < NRT / 2; ++rtp) {
                f32x4 acc0 = {0.f, 0.f, 0.f, 0.f};
                f32x4 acc1 = {0.f, 0.f, 0.f, 0.f};
#pragma unroll
                for (int kf = 0; kf < KF; ++kf) {
                    const bf16x8 a0 = ldsA[((2 * rtp) * KF + kf) * 64 + (lane ^ kf)];
                    const bf16x8 a1 = ldsA[((2 * rtp + 1) * KF + kf) * 64 + (lane ^ kf)];
                    acc0 = __builtin_amdgcn_mfma_f32_16x16x32_bf16(w[kf], a0, acc0, 0, 0, 0);
                    acc1 = __builtin_amdgcn_mfma_f32_16x16x32_bf16(w[kf], a1, acc1, 0, 0, 0);
                }
                const int r0g = row0 + 2 * rtp * 16 + rf;
                const int r1g = r0g + 16;
                const int c4 = tcol + 4 * kg;
                ushort4 q0 = {f2bu(acc0[0]), f2bu(acc0[1]), f2bu(acc0[2]), f2bu(acc0[3])};
                ushort4 q1 = {f2bu(acc1[0]), f2bu(acc1[1]), f2bu(acc1[2]), f2bu(acc1[3])};
                if (isft) {
                    if (r0g < M)
                        *reinterpret_cast<ushort4*>(&ftb[(size_t)r0g * ldft + c4]) = q0;
                    if (r1g < M)
                        *reinterpret_cast<ushort4*>(&ftb[(size_t)r1g * ldft + c4]) = q1;
                } else {
                    if (r0g < M) {
                        __hip_bfloat16* hp = hout + (size_t)r0g * ldh + houtoff + c4;
                        if (ADDRES) {
                            ushort4 cur = *reinterpret_cast<ushort4*>(hp);
                            q0.x = f2bu(bf2f(cur.x) + acc0[0]);
                            q0.y = f2bu(bf2f(cur.y) + acc0[1]);
                            q0.z = f2bu(bf2f(cur.z) + acc0[2]);
                            q0.w = f2bu(bf2f(cur.w) + acc0[3]);
                        }
                        *reinterpret_cast<ushort4*>(hp) = q0;
                    }
                    if (r1g < M) {
                        __hip_bfloat16* hp = hout + (size_t)r1g * ldh + houtoff + c4;
                        if (ADDRES) {
                            ushort4 cur = *reinterpret_cast<ushort4*>(hp);
                            q1.x = f2bu(bf2f(cur.x) + acc1[0]);
                            q1.y = f2bu(bf2f(cur.y) + acc1[1]);
                            q1.z = f2bu(bf2f(cur.z) + acc1[2]);
                            q1.w = f2bu(bf2f(cur.w) + acc1[3]);
                        }
                        *reinterpret_cast<ushort4*>(hp) = q1;
                    }
                }
            }
        }

        // ---- aug tile (el/er), wave 0 only ----
        if (wv == 0) {
            bf16x8 w[KF];
            const __hip_bfloat16* bp = Waug + (size_t)(NF + rf) * K + kg * 8;
#pragma unroll
            for (int kf = 0; kf < KF; ++kf) w[kf] = ldb8(bp + kf * 32);
#pragma unroll
            for (int rtp = 0; rtp < NRT / 2; ++rtp) {
                f32x4 acc0 = {0.f, 0.f, 0.f, 0.f};
                f32x4 acc1 = {0.f, 0.f, 0.f, 0.f};
#pragma unroll
                for (int kf = 0; kf < KF; ++kf) {
                    const bf16x8 a0 = ldsA[((2 * rtp) * KF + kf) * 64 + (lane ^ kf)];
                    const bf16x8 a1 = ldsA[((2 * rtp + 1) * KF + kf) * 64 + (lane ^ kf)];
                    acc0 = __builtin_amdgcn_mfma_f32_16x16x32_bf16(w[kf], a0, acc0, 0, 0, 0);
                    acc1 = __builtin_amdgcn_mfma_f32_16x16x32_bf16(w[kf], a1, acc1, 0, 0, 0);
                }
                const int r0g = row0 + 2 * rtp * 16 + rf;
                const int r1g = r0g + 16;
                if (kg == 0) {
                    if (r0g < M) {
                        const float o = oi[r0g];
                        float4 v = {acc0[0] * o, acc0[1] * o, acc0[2] * o, acc0[3] * o};
                        *reinterpret_cast<float4*>(&el[(size_t)r0g * 4]) = v;
                    }
                    if (r1g < M) {
                        const float o = oi[r1g];
                        float4 v = {acc1[0] * o, acc1[1] * o, acc1[2] * o, acc1[3] * o};
                        *reinterpret_cast<float4*>(&el[(size_t)r1g * 4]) = v;
                    }
                } else if (kg == 1) {
                    if (r0g < M) {
                        float4 v = {acc0[0], acc0[1], acc0[2], acc0[3]};
                        *reinterpret_cast<float4*>(&er[(size_t)r0g * 4]) = v;
                    }
                    if (r1g < M) {
                        float4 v = {acc1[0], acc1[1], acc1[2], acc1[3]};
                        *reinterpret_cast<float4*>(&er[(size_t)r1g * 4]) = v;
                    }
                }
            }
        }
        __syncthreads();        // LDS safe to overwrite next iteration
        t = tn;
    }
}

// -------- small merged GATConv (last layer, NOUT=40), bf16 A -------------
template<int K, int NF, int NR, int H>
__global__ __launch_bounds__(256) void k_gatconv_sm(
    const __hip_bfloat16* __restrict__ A, int lda,
    const __hip_bfloat16* __restrict__ Wft,
    const __hip_bfloat16* __restrict__ Wres,
    __hip_bfloat16* __restrict__ ftb, int ldft,
    float* __restrict__ Cres, int ldcres,
    int M,
    const float* __restrict__ scale, const float* __restrict__ shift,
    const float* __restrict__ bias,
    const float* __restrict__ attn_l, const float* __restrict__ attn_r,
    const float* __restrict__ oi,
    float* __restrict__ el, float* __restrict__ er) {
    constexpr int KF   = K / 32;
    constexpr int NCTF = (NF + 15) / 16;
    constexpr int NCTR = (NR + 15) / 16;
    constexpr int CTH  = NCTF / H;
    static_assert(NCTF % H == 0, "head tiling");
    const int wave = threadIdx.x >> 6, lane = threadIdx.x & 63;
    const int row0 = blockIdx.x * 64 + wave * 16;
    const int rf = lane & 15, kg = lane >> 4;

    bf16x8 a[KF];
    {
        const int row = row0 + rf;
        const bool rok = row < M;
#pragma unroll
        for (int kf = 0; kf < KF; ++kf) {
            const int c0 = kg * 8 + kf * 32;
            if (rok) {
                bf16x8 raw = ldb8(A + (size_t)row * lda + c0);
                float4 s01 = *reinterpret_cast<const float4*>(scale + c0);
                float4 s23 = *reinterpret_cast<const float4*>(scale + c0 + 4);
                float4 h01 = *reinterpret_cast<const float4*>(shift + c0);
                float4 h23 = *reinterpret_cast<const float4*>(shift + c0 + 4);
                float sc[8] = {s01.x,s01.y,s01.z,s01.w,s23.x,s23.y,s23.z,s23.w};
                float sh[8] = {h01.x,h01.y,h01.z,h01.w,h23.x,h23.y,h23.z,h23.w};
                bf16x8 t;
#pragma unroll
                for (int i = 0; i < 8; ++i)
                    t[i] = (__bf16)fmaxf((float)raw[i] * sc[i] + sh[i], 0.f);
                a[kf] = t;
            } else {
                a[kf] = zb8();
            }
        }
    }

    int ct = 0;
    for (int hh = 0; hh < H; ++hh) {
        float elp[4] = {0.f, 0.f, 0.f, 0.f};
        float erp[4] = {0.f, 0.f, 0.f, 0.f};
        for (int cth = 0; cth < CTH; ++cth, ++ct) {
            const int ccol = ct * 16 + rf;
            bf16x8 b[KF];
            const __hip_bfloat16* bp = Wft + (size_t)ccol * K + kg * 8;
#pragma unroll
            for (int kf = 0; kf < KF; ++kf)
                b[kf] = (ccol < NF) ? ldb8(bp + kf * 32) : zb8();
            f32x4 acc = {0.f, 0.f, 0.f, 0.f};
#pragma unroll
            for (int kf = 0; kf < KF; ++kf)
                acc = __builtin_amdgcn_mfma_f32_16x16x32_bf16(a[kf], b[kf], acc, 0, 0, 0);
            float al = 0.f, ar = 0.f;
            if (ccol < NF) { al = attn_l[ccol]; ar = attn_r[ccol]; }
            if (ccol < NF) {
#pragma unroll
                for (int r = 0; r < 4; ++r) {
                    const float v = acc[r];
                    elp[r] += v * al; erp[r] += v * ar;
                    const int row = row0 + kg * 4 + r;
                    if (row < M)
                        ftb[(size_t)row * ldft + ccol] = __float2bfloat16(v);
                }
            }
        }
#pragma unroll
        for (int off = 1; off <= 8; off <<= 1)
#pragma unroll
            for (int r = 0; r < 4; ++r) {
                elp[r] += __shfl_xor(elp[r], off);
                erp[r] += __shfl_xor(erp[r], off);
            }
        if (rf == 0) {
#pragma unroll
            for (int r = 0; r < 4; ++r) {
                const int row = row0 + kg * 4 + r;
                if (row < M) {
                    el[(size_t)row * H + hh] = oi[row] * elp[r];
                    er[(size_t)row * H + hh] = erp[r];
                }
            }
        }
    }

    for (int rt = 0; rt < NCTR; ++rt) {
        const int ccol = rt * 16 + rf;
        bf16x8 b[KF];
        const __hip_bfloat16* bp = Wres + (size_t)ccol * K + kg * 8;
#pragma unroll
        for (int kf = 0; kf < KF; ++kf)
            b[kf] = (ccol < NR) ? ldb8(bp + kf * 32) : zb8();
        f32x4 acc = {0.f, 0.f, 0.f, 0.f};
#pragma unroll
        for (int kf = 0; kf < KF; ++kf)
            acc = __builtin_amdgcn_mfma_f32_16x16x32_bf16(a[kf], b[kf], acc, 0, 0, 0);
        if (ccol < NR) {
#pragma unroll
            for (int r = 0; r < 4; ++r) {
                const int row = row0 + kg * 4 + r;
                if (row < M) {
                    float v = acc[r];
                    if (bias) v += bias[ccol];
                    Cres[(size_t)row * ldcres + ccol] = v;
                }
            }
        }
    }
}

// ------------- fused edge softmax + message aggregation (per dst) ---------
template<int EPL>
__device__ inline void ldrow(const __hip_bfloat16* fp, float* f) {
    if constexpr (EPL == 8) {
        bf16x8 q = ldb8(fp);
#pragma unroll
        for (int i = 0; i < 8; ++i) f[i] = (float)q[i];
    } else if constexpr (EPL == 4) {
        ushort4 q = *reinterpret_cast<const ushort4*>(fp);
        f[0] = bf2f(q.x); f[1] = bf2f(q.y); f[2] = bf2f(q.z); f[3] = bf2f(q.w);
    } else if constexpr (EPL == 2) {
        ushort2 q = *reinterpret_cast<const ushort2*>(fp);
        f[0] = bf2f(q.x); f[1] = bf2f(q.y);
    } else {
        f[0] = bf2f(*reinterpret_cast<const unsigned short*>(fp));
    }
}
__device__ inline float escore(float sc) {
    sc = sc >= 0.f ? sc : 0.2f * sc;
    sc = fminf(fmaxf(sc, -30.f), 30.f);
    return __expf(sc);
}

// LW = lanes per node (64/32/16). 256 thr -> 256/LW nodes per block.
// EPL = W/LW elements per lane. OBF: out is bf16 (RMW); else f32.
template<int H, int D, int LW, bool OBF>
__global__ __launch_bounds__(256) void k_agg(
    const __hip_bfloat16* __restrict__ ftb,
    const float* __restrict__ el, const float* __restrict__ er,
    const int* __restrict__ row_ptr, const int* __restrict__ csr_src,
    const float* __restrict__ oi, const float* __restrict__ insq,
    void* __restrict__ out, int ldc, int N) {
    constexpr int W = H * D;
    constexpr int EPL = (W >= LW) ? (W / LW) : 1;
    constexpr int NPB = 256 / LW;
    const int lane = threadIdx.x % LW;
    const int v = blockIdx.x * NPB + (threadIdx.x / LW);
    if (v >= N) return;
    if (W < LW && lane >= W) return;
    const int col0 = lane * EPL;
    const int myh = (W >= LW) ? (col0 / D) : 0;
    const int s = row_ptr[v], e = row_ptr[v + 1];
    const float erv = er[(size_t)v * H + myh];

    float denom = 0.f;
    float acc[EPL];
#pragma unroll
    for (int k = 0; k < EPL; ++k) acc[k] = 0.f;

    int p = s;
    for (; p + 3 < e; p += 4) {
        const int u0 = csr_src[p + 0], u1 = csr_src[p + 1];
        const int u2 = csr_src[p + 2], u3 = csr_src[p + 3];
        float f0[EPL], f1[EPL], f2[EPL], f3[EPL];
        ldrow<EPL>(ftb + (size_t)u0 * W + col0, f0);
        ldrow<EPL>(ftb + (size_t)u1 * W + col0, f1);
        ldrow<EPL>(ftb + (size_t)u2 * W + col0, f2);
        ldrow<EPL>(ftb + (size_t)u3 * W + col0, f3);
        const float s0 = el[(size_t)u0 * H + myh], s1 = el[(size_t)u1 * H + myh];
        const float s2 = el[(size_t)u2 * H + myh], s3 = el[(size_t)u3 * H + myh];
        const float o0 = oi[u0], o1 = oi[u1], o2 = oi[u2], o3 = oi[u3];
        const float w0 = escore(s0 + erv), w1 = escore(s1 + erv);
        const float w2 = escore(s2 + erv), w3 = escore(s3 + erv);
        denom += (w0 + w1) + (w2 + w3);
        const float a0 = w0 * o0, a1 = w1 * o1, a2 = w2 * o2, a3 = w3 * o3;
#pragma unroll
        for (int k = 0; k < EPL; ++k)
            acc[k] += a0 * f0[k] + a1 * f1[k] + a2 * f2[k] + a3 * f3[k];
    }
    for (; p < e; ++p) {
        const int u = csr_src[p];
        float f[EPL];
        ldrow<EPL>(ftb + (size_t)u * W + col0, f);
        const float w = escore(el[(size_t)u * H + myh] + erv);
        denom += w;
        const float a = w * oi[u];
#pragma unroll
        for (int k = 0; k < EPL; ++k) acc[k] += a * f[k];
    }

    const float iv = insq[v] / fmaxf(denom, 1e-9f);
    if (OBF) {
        __hip_bfloat16* op = (__hip_bfloat16*)out + (size_t)v * ldc + col0;
        if constexpr (EPL == 8) {
            bf16x8 o = *reinterpret_cast<bf16x8*>(op);
            bf16x8 q;
#pragma unroll
            for (int i = 0; i < 8; ++i)
                q[i] = (__bf16)((float)o[i] + iv * acc[i]);
            *reinterpret_cast<bf16x8*>(op) = q;
        } else if constexpr (EPL == 4) {
            ushort4 o = *reinterpret_cast<ushort4*>(op);
            o.x = f2bu(bf2f(o.x) + iv * acc[0]);
            o.y = f2bu(bf2f(o.y) + iv * acc[1]);
            o.z = f2bu(bf2f(o.z) + iv * acc[2]);
            o.w = f2bu(bf2f(o.w) + iv * acc[3]);
            *reinterpret_cast<ushort4*>(op) = o;
        } else if constexpr (EPL == 2) {
            ushort2 o = *reinterpret_cast<ushort2*>(op);
            o.x = f2bu(bf2f(o.x) + iv * acc[0]);
            o.y = f2bu(bf2f(o.y) + iv * acc[1]);
            *reinterpret_cast<ushort2*>(op) = o;
        } else {
            unsigned short* up = (unsigned short*)op;
            *up = f2bu(bf2f(*up) + iv * acc[0]);
        }
    } else {
        float* op = (float*)out + (size_t)v * ldc + col0;
        if constexpr (EPL == 8) {
            float4 o0 = *reinterpret_cast<float4*>(op);
            float4 o1 = *reinterpret_cast<float4*>(op + 4);
            o0.x += iv * acc[0]; o0.y += iv * acc[1];
            o0.z += iv * acc[2]; o0.w += iv * acc[3];
            o1.x += iv * acc[4]; o1.y += iv * acc[5];
            o1.z += iv * acc[6]; o1.w += iv * acc[7];
            *reinterpret_cast<float4*>(op) = o0;
            *reinterpret_cast<float4*>(op + 4) = o1;
        } else if constexpr (EPL == 4) {
            float4 o = *reinterpret_cast<float4*>(op);
            o.x += iv * acc[0]; o.y += iv * acc[1]; o.z += iv * acc[2]; o.w += iv * acc[3];
            *reinterpret_cast<float4*>(op) = o;
        } else if constexpr (EPL == 2) {
            float2 o = *reinterpret_cast<float2*>(op);
            o.x += iv * acc[0]; o.y += iv * acc[1];
            *reinterpret_cast<float2*>(op) = o;
        } else {
            op[0] += iv * acc[0];
        }
    }
}

// ------------------------------ batch norm (bf16 input) -------------------
template<int F>
__global__ __launch_bounds__(256) void k_bn_part(const __hip_bfloat16* __restrict__ in,
                                                 int ldin, int N,
                                                 float* __restrict__ psum,
                                                 float* __restrict__ psum2) {
    constexpr int CP = F / 2;                 // col pairs
    constexpr int SL = 256 / CP;              // rows per block pass
    const int cp = threadIdx.x % CP;
    const int pr = blockIdx.x * SL + threadIdx.x / CP;
    const int PRT = gridDim.x * SL;
    float s0 = 0.f, s20 = 0.f, s1 = 0.f, s21 = 0.f;
    for (int r = pr; r < N; r += PRT) {
        ushort2 q = *reinterpret_cast<const ushort2*>(&in[(size_t)r * ldin + cp * 2]);
        const float a = bf2f(q.x), b = bf2f(q.y);
        s0 += a; s20 += a * a; s1 += b; s21 += b * b;
    }
    psum[(size_t)pr * F + cp * 2] = s0;
    psum[(size_t)pr * F + cp * 2 + 1] = s1;
    psum2[(size_t)pr * F + cp * 2] = s20;
    psum2[(size_t)pr * F + cp * 2 + 1] = s21;
}

template<int F>
__global__ __launch_bounds__(256) void k_bn_fin(const float* __restrict__ psum,
                                                const float* __restrict__ psum2, int PRT,
                                                const float* __restrict__ gamma,
                                                const float* __restrict__ beta,
                                                float* __restrict__ scale,
                                                float* __restrict__ shift, int N) {
    const int col = blockIdx.x;
    float s = 0.f, s2 = 0.f;
    for (int p = threadIdx.x; p < PRT; p += 256) {
        s += psum[(size_t)p * F + col];
        s2 += psum2[(size_t)p * F + col];
    }
#pragma unroll
    for (int off = 32; off; off >>= 1) {
        s += __shfl_down(s, off);
        s2 += __shfl_down(s2, off);
    }
    __shared__ float sm[4], sm2[4];
    const int wave = threadIdx.x >> 6, lane = threadIdx.x & 63;
    if (lane == 0) { sm[wave] = s; sm2[wave] = s2; }
    __syncthreads();
    if (threadIdx.x == 0) {
        s = sm[0] + sm[1] + sm[2] + sm[3];
        s2 = sm2[0] + sm2[1] + sm2[2] + sm2[3];
        float mu = s / N;
        float var = s2 / N - mu * mu;
        float isd = rsqrtf(var + 1e-5f);
        float g = gamma[col];
        scale[col] = g * isd;
        shift[col] = beta[col] - g * isd * mu;
    }
}

// ------------------------------- launcher ---------------------------------
extern "C" void kernel_launch(void* const* d_in, const int* in_sizes, int n_in,
                              void* d_out, int out_size, void* d_ws, size_t ws_size,
                              hipStream_t stream) {
    const float* x           = (const float*)d_in[0];
    const int*   src         = (const int*)d_in[1];
    const int*   dst         = (const int*)d_in[2];
    const float* W0          = (const float*)d_in[3];
    const float* attn_l0     = (const float*)d_in[4];
    const float* attn_r0     = (const float*)d_in[5];
    const float* resW0       = (const float*)d_in[6];
    const float* mid_bn_g    = (const float*)d_in[7];
    const float* mid_bn_b    = (const float*)d_in[8];
    const float* mid_W       = (const float*)d_in[9];
    const float* mid_attn_l  = (const float*)d_in[10];
    const float* mid_attn_r  = (const float*)d_in[11];
    const float* mid_resW    = (const float*)d_in[12];
    const float* norm_gamma  = (const float*)d_in[13];
    const float* norm_beta   = (const float*)d_in[14];
    const float* W_last      = (const float*)d_in[15];
    const float* attn_l_last = (const float*)d_in[16];
    const float* attn_r_last = (const float*)d_in[17];
    const float* resW_last   = (const float*)d_in[18];
    const float* bias_last   = (const float*)d_in[19];

    const int N = in_sizes[0] / IN_F;
    const int E = in_sizes[1];

    // ---- workspace carve-up (256B aligned) ----
    char* p = (char*)d_ws;
    size_t used = 0;
    auto take = [&](size_t bytes) -> char* {
        char* r = p;
        size_t adv = (bytes + 255) & ~(size_t)255;
        p += adv; used += adv;
        return r;
    };
    __hip_bfloat16* h       = (__hip_bfloat16*)take((size_t)N * HIDW * 2);
    __hip_bfloat16* ftb     = (__hip_bfloat16*)take((size_t)N * HIDW * 2);
    float*          el      = (float*)take((size_t)N * 4 * 4);
    float*          er      = (float*)take((size_t)N * 4 * 4);
    float*          oi      = (float*)take((size_t)N * 4);
    float*          insq    = (float*)take((size_t)N * 4);
    int*            indeg   = (int*)take((size_t)N * 4);
    int*            outdeg  = (int*)take((size_t)N * 4);
    int*            row_ptr = (int*)take((size_t)(N + 1) * 4);
    int*            cursor  = (int*)take((size_t)N * 4);
    int*            csr_src = (int*)take((size_t)E * 4);
    int*            bsum    = (int*)take(256 * 4);
    float*          psum    = (float*)take(1 << 20);
    float*          psum2   = (float*)take(1 << 20);
    float*          scale   = (float*)take(1024);
    float*          shift   = (float*)take(1024);
    __hip_bfloat16* Waug0     = (__hip_bfloat16*)take((size_t)272 * 256 * 2);
    __hip_bfloat16* midWaug   = (__hip_bfloat16*)take((size_t)4 * 144 * 128 * 2);
    __hip_bfloat16* resW0bf   = (__hip_bfloat16*)take(65536 * 2);
    __hip_bfloat16* midresWbf = (__hip_bfloat16*)take(65536 * 2);
    __hip_bfloat16* Wlastbf   = (__hip_bfloat16*)take(10240 * 2);
    __hip_bfloat16* resWlastbf= (__hip_bfloat16*)take(10240 * 2);
    if (used > ws_size) return;   // out of workspace: leave output poisoned (visible failure)

    const int nbN = (N + 255) / 256;
    const int NB4 = (N + 3) / 4;
    const int NB8 = (N + 7) / 8;
    const int NB16 = (N + 15) / 16;
    const int NT  = (N + 63) / 64;              // GEMM row-tiles (BM=64)
    const int GWP = (NT + 1) / 2;               // pipelined: 2 tiles/block
    const int GWS = (N + 63) / 64;              // small kernel: 64 rows/block
    const int BNB = 512;                        // BN partial blocks

    // ---- graph prep ----
    hipMemsetAsync(indeg, 0, (size_t)N * 4, stream);
    hipMemsetAsync(outdeg, 0, (size_t)N * 4, stream);
    k_hist<<<1024, 256, 0, stream>>>(src, dst, E, outdeg, indeg);
    k_scan1<<<nbN, 256, 0, stream>>>(indeg, N, row_ptr + 1, bsum);
    k_scan2<<<1, 256, 0, stream>>>(bsum, nbN);
    k_scan3<<<nbN, 256, 0, stream>>>(row_ptr + 1, bsum, N);
    hipMemcpyAsync(cursor, row_ptr, (size_t)N * 4, hipMemcpyDeviceToDevice, stream);
    k_scatter<<<1024, 256, 0, stream>>>(src, dst, E, cursor, csr_src);
    k_deg<<<nbN, 256, 0, stream>>>(outdeg, indeg, oi, insq, N);

    // ---- weight conversion + augmentation ----
    k_cvt6<<<dim3(64, 4), 256, 0, stream>>>(resW0, resW0bf, 65536,
                                            mid_resW, midresWbf, 65536,
                                            W_last, Wlastbf, 10240,
                                            resW_last, resWlastbf, 10240,
                                            nullptr, nullptr, 0,
                                            nullptr, nullptr, 0);
    k_prepw<<<dim3(96, 5), 256, 0, stream>>>(W0, attn_l0, attn_r0,
                                             mid_W, mid_attn_l, mid_attn_r,
                                             Waug0, midWaug);

    // ---- layer 0: GATConv(256 -> 4x64), A = x (f32, no BN) ----
    k_gatconv_lds<256, 256, 256, 4, false, false, false><<<GWP, 512, 0, stream>>>(
        x, 256, Waug0, resW0bf, ftb, 256, h, 256, 0, N, NT,
        nullptr, nullptr, oi, el, er);
    k_agg<4, 64, 32, true><<<NB8, 256, 0, stream>>>(ftb, el, er, row_ptr, csr_src,
                                                    oi, insq, h, 256, N);

    // ---- reversible middle layers ----
    for (int l = 0; l < 2; ++l) {
        for (int g = 0; g < 2; ++g) {
            const int inoff  = (g == 0) ? 128 : 0;
            const int outoff = (g == 0) ? 0 : 128;
            const int pg = l * 2 + g;
            k_bn_part<128><<<BNB, 256, 0, stream>>>(h + inoff, 256, N, psum, psum2);
            k_bn_fin<128><<<128, 256, 0, stream>>>(psum, psum2, BNB * 4,
                                                   mid_bn_g + pg * 128, mid_bn_b + pg * 128,
                                                   scale, shift, N);
            k_gatconv_lds<128, 128, 128, 4, true, true, true><<<GWP, 512, 0, stream>>>(
                h + inoff, 256, midWaug + (size_t)pg * 144 * 128, midresWbf + pg * 16384,
                ftb, 128, h, 256, outoff, N, NT,
                scale, shift, oi, el, er);
            k_agg<4, 32, 16, true><<<NB16, 256, 0, stream>>>(ftb, el, er, row_ptr, csr_src,
                                                             oi, insq, h + outoff, 256, N);
        }
    }

    // ---- final norm + GATConv(256 -> 1x40) + bias ----
    k_bn_part<256><<<BNB, 256, 0, stream>>>(h, 256, N, psum, psum2);
    k_bn_fin<256><<<256, 256, 0, stream>>>(psum, psum2, BNB * 2, norm_gamma, norm_beta,
                                           scale, shift, N);
    k_gatconv_sm<256, 40, 40, 1><<<GWS, 256, 0, stream>>>(
        h, 256, Wlastbf, resWlastbf, ftb, 40, (float*)d_out, 40, N,
        scale, shift, bias_last,
        attn_l_last, attn_r_last, oi, el, er);
    k_agg<1, 40, 64, false><<<NB4, 256, 0, stream>>>(ftb, el, er, row_ptr, csr_src,
                                                     oi, insq, (float*)d_out, 40, N);
}